// Round 5
// baseline (198.343 us; speedup 1.0000x reference)
//
#include <hip/hip_runtime.h>
#include <cstdint>
#include <cstddef>

// ---------------------------------------------------------------------------
// HierarchicalSparseAttention  B=2 L=4096 D=1024 H=16 DH=64
// cvt(f32->bf16) -> QKV GEMM (8-phase 128x256 bf16 MFMA) -> tree build ->
// sparse attn -> output GEMM (8-phase, +bias, f32)
// ---------------------------------------------------------------------------

typedef __bf16 bf16;
typedef __bf16 bf16x8 __attribute__((ext_vector_type(8)));
typedef __bf16 bf16x4 __attribute__((ext_vector_type(4)));
typedef float  f32x4  __attribute__((ext_vector_type(4)));

#define L_SEQ  4096
#define NFLAT  8192   /* padded 2L-1 = 8191 */

__device__ __forceinline__ int off_l(int l) { return 8192 - (8192 >> l); }

// ---- async global->LDS, 16B per lane; lds base must be wave-uniform --------
__device__ __forceinline__ void glds16(const bf16* g, bf16* l) {
  __builtin_amdgcn_global_load_lds(
      (const __attribute__((address_space(1))) unsigned int*)g,
      (__attribute__((address_space(3))) unsigned int*)l, 16, 0, 0);
}

#define MEMFENCE asm volatile("" ::: "memory")
__device__ __forceinline__ void barrier_raw() {
  MEMFENCE; __builtin_amdgcn_s_barrier(); MEMFENCE;
}

// st_16x32 XOR swizzle (involution; permutes 16B chunks, preserves alignment)
__device__ __forceinline__ int swz(int b) { return b ^ (((b >> 9) & 1) << 5); }
// logical byte addr of (row, col) in a [R][64] bf16 tile stored as [16][32]
// subtiles (1024B each), 2 col-blocks per row-block
__device__ __forceinline__ int la(int row, int col) {
  return ((((row >> 4) << 1) + (col >> 5)) << 10) + ((row & 15) << 6) + ((col & 31) << 1);
}

// ---------------------------------------------------------------------------
// fp32 -> bf16 conversions (2 launches total)
// ---------------------------------------------------------------------------
__global__ __launch_bounds__(256) void cvt3_kernel(
    const float* __restrict__ a, const float* __restrict__ b, const float* __restrict__ c,
    bf16* __restrict__ x, bf16* __restrict__ y, bf16* __restrict__ z) {
  const int s = blockIdx.y;
  const float* src = (s == 0) ? a : (s == 1) ? b : c;
  bf16*        dst = (s == 0) ? x : (s == 1) ? y : z;
  const int i = blockIdx.x * 256 + threadIdx.x;   // < 2097152 by grid
  const float4 v = ((const float4*)src)[i];
  bf16x4 o;
  o[0] = (bf16)v.x; o[1] = (bf16)v.y; o[2] = (bf16)v.z; o[3] = (bf16)v.w;
  *(bf16x4*)(dst + (size_t)i * 4) = o;
}

__global__ __launch_bounds__(256) void cvt4_kernel(
    const float* __restrict__ a, const float* __restrict__ b,
    const float* __restrict__ c, const float* __restrict__ d,
    bf16* __restrict__ x, bf16* __restrict__ y, bf16* __restrict__ z, bf16* __restrict__ w) {
  const int s = blockIdx.y;
  const float* src = (s == 0) ? a : (s == 1) ? b : (s == 2) ? c : d;
  bf16*        dst = (s == 0) ? x : (s == 1) ? y : (s == 2) ? z : w;
  const int i = blockIdx.x * 256 + threadIdx.x;   // < 262144 by grid
  const float4 v = ((const float4*)src)[i];
  bf16x4 o;
  o[0] = (bf16)v.x; o[1] = (bf16)v.y; o[2] = (bf16)v.z; o[3] = (bf16)v.w;
  *(bf16x4*)(dst + (size_t)i * 4) = o;
}

// ---------------------------------------------------------------------------
// 8-phase GEMM core: C(128x256) = A(128xK) * W(256xK)^T, K=1024, BK=64.
// 512 threads = 8 waves (2M x 4N); wave output 64x64 = 4x4 frags 16x16x32.
// Double-buffered swizzled LDS; counted vmcnt; raw barriers; setprio on MFMA.
// Staging: global_load_lds with LINEAR dest + inverse-swizzled SOURCE (rule 21).
// ---------------------------------------------------------------------------
__device__ __forceinline__ void stage_tile(const bf16* __restrict__ A,
                                           const bf16* __restrict__ W,
                                           int tm, int tn, int k0,
                                           bf16* AsP, bf16* BsP, int wid, int lane) {
  // A: 128x64 tile = 16KB = 2 wave-loads; B: 256x64 = 32KB = 4 wave-loads
#pragma unroll
  for (int i = 0; i < 2; i++) {
    const int d  = i * 8192 + wid * 1024 + lane * 16;
    const int lb = swz(d);
    const int row = ((lb >> 10) >> 1) * 16 + ((lb >> 6) & 15);
    const int col = ((lb >> 10) & 1) * 32 + ((lb & 63) >> 1);
    glds16(A + (size_t)(tm * 128 + row) * 1024 + k0 + col, AsP + i * 4096 + wid * 512);
  }
#pragma unroll
  for (int i = 0; i < 4; i++) {
    const int d  = i * 8192 + wid * 1024 + lane * 16;
    const int lb = swz(d);
    const int row = ((lb >> 10) >> 1) * 16 + ((lb >> 6) & 15);
    const int col = ((lb >> 10) & 1) * 32 + ((lb & 63) >> 1);
    glds16(W + (size_t)(tn * 256 + row) * 1024 + k0 + col, BsP + i * 4096 + wid * 512);
  }
}

__device__ __forceinline__ void gemm8_core(const bf16* __restrict__ A,
                                           const bf16* __restrict__ W,
                                           int tm, int tn,
                                           bf16 (*As)[128 * 64], bf16 (*Bs)[256 * 64],
                                           f32x4 (&acc)[4][4]) {
  const int tid  = threadIdx.x;
  const int wid  = tid >> 6, lane = tid & 63;
  const int wm2  = wid >> 2, wn4 = wid & 3;
  const int laneR  = lane & 15;
  const int laneC8 = (lane >> 4) * 8;

  // prologue: tile0 -> buf0, tile1 -> buf1
  stage_tile(A, W, tm, tn, 0,  As[0], Bs[0], wid, lane);
  stage_tile(A, W, tm, tn, 64, As[1], Bs[1], wid, lane);
  asm volatile("s_waitcnt vmcnt(6)" ::: "memory");   // tile0's 6 loads done
  barrier_raw();

  for (int t = 0; t < 16; ++t) {
    const int p = t & 1;
    const char* Ab = (const char*)As[p];
    const char* Bb = (const char*)Bs[p];
#pragma unroll
    for (int q = 0; q < 2; ++q) {
      // ---- ds_read: A frags fr = 2q..2q+1, all B frags (12 x ds_read_b128)
      bf16x8 af[2][2], bfr[4][2];
#pragma unroll
      for (int f = 0; f < 2; f++)
#pragma unroll
        for (int ks = 0; ks < 2; ks++) {
          const int row = wm2 * 64 + (2 * q + f) * 16 + laneR;
          af[f][ks] = *(const bf16x8*)(Ab + swz(la(row, ks * 32 + laneC8)));
        }
#pragma unroll
      for (int f = 0; f < 4; f++)
#pragma unroll
        for (int ks = 0; ks < 2; ks++) {
          const int row = wn4 * 64 + f * 16 + laneR;
          bfr[f][ks] = *(const bf16x8*)(Bb + swz(la(row, ks * 32 + laneC8)));
        }
      // ---- stage tile t+1 into freed buffer (phase 0 only; front-loaded)
      if (q == 0 && t >= 1 && t < 15)
        stage_tile(A, W, tm, tn, (t + 1) << 6, As[p ^ 1], Bs[p ^ 1], wid, lane);
      barrier_raw();
      // ---- 16 MFMA
      __builtin_amdgcn_s_setprio(1);
#pragma unroll
      for (int f = 0; f < 2; f++)
#pragma unroll
        for (int j = 0; j < 4; j++)
#pragma unroll
          for (int ks = 0; ks < 2; ks++)
            acc[2 * q + f][j] = __builtin_amdgcn_mfma_f32_16x16x32_bf16(
                af[f][ks], bfr[j][ks], acc[2 * q + f][j], 0, 0, 0);
      __builtin_amdgcn_s_setprio(0);
      // ---- tile boundary: require next tile's staging complete (counted wait)
      if (q == 1 && t < 15)
        asm volatile("s_waitcnt vmcnt(0)" ::: "memory");
      barrier_raw();
    }
  }
}

// QKV projections. grid = (256, 3): x -> (tm = x>>2, tn = x&3), y -> {Q,K,V}
// Writes Q -> [bh][l][64], K/V -> flat level-0 [bh][node][64].
__global__ __launch_bounds__(512, 2) void gemm8_qkv_kernel(
    const bf16* __restrict__ qx, const bf16* __restrict__ kx, const bf16* __restrict__ vx,
    const bf16* __restrict__ wq, const bf16* __restrict__ wk, const bf16* __restrict__ wv,
    bf16* __restrict__ Qb, bf16* __restrict__ fK, bf16* __restrict__ fV) {
  __shared__ __align__(16) bf16 As[2][128 * 64];
  __shared__ __align__(16) bf16 Bs[2][256 * 64];
  const int z = blockIdx.y;
  const bf16* A = (z == 0) ? qx : (z == 1) ? kx : vx;
  const bf16* W = (z == 0) ? wq : (z == 1) ? wk : wv;
  bf16* D       = (z == 0) ? Qb : (z == 1) ? fK : fV;
  const int lstr = (z == 0) ? L_SEQ : NFLAT;
  const int tm = blockIdx.x >> 2, tn = blockIdx.x & 3;
  f32x4 acc[4][4] = {};
  gemm8_core(A, W, tm, tn, As, Bs, acc);
  const int lane = threadIdx.x & 63, wid = threadIdx.x >> 6;
  const int m0 = tm * 128 + (wid >> 2) * 64 + (lane >> 4) * 4;
  const int n0 = tn * 256 + (wid & 3) * 64 + (lane & 15);
#pragma unroll
  for (int i = 0; i < 4; i++)
#pragma unroll
    for (int j = 0; j < 4; j++)
#pragma unroll
      for (int r = 0; r < 4; r++) {
        const int m = m0 + i * 16 + r;
        const int n = n0 + j * 16;
        const int b = m >> 12, l = m & 4095;
        const int h = n >> 6,  dh = n & 63;
        D[((size_t)(b * 16 + h) * lstr + l) * 64 + dh] = (bf16)acc[i][j][r];
      }
}

// Output projection + bias, f32 out (8192 x 1024). grid = 256.
__global__ __launch_bounds__(512, 2) void gemm8_out_kernel(
    const bf16* __restrict__ Ob, const bf16* __restrict__ wo,
    const float* __restrict__ bo, float* __restrict__ out) {
  __shared__ __align__(16) bf16 As[2][128 * 64];
  __shared__ __align__(16) bf16 Bs[2][256 * 64];
  const int tm = blockIdx.x >> 2, tn = blockIdx.x & 3;
  f32x4 acc[4][4] = {};
  gemm8_core(Ob, wo, tm, tn, As, Bs, acc);
  const int lane = threadIdx.x & 63, wid = threadIdx.x >> 6;
  const int m0 = tm * 128 + (wid >> 2) * 64 + (lane >> 4) * 4;
  const int n0 = tn * 256 + (wid & 3) * 64 + (lane & 15);
#pragma unroll
  for (int i = 0; i < 4; i++)
#pragma unroll
    for (int j = 0; j < 4; j++)
#pragma unroll
      for (int r = 0; r < 4; r++) {
        const int m = m0 + i * 16 + r;
        const int n = n0 + j * 16;
        out[(size_t)m * 1024 + n] = acc[i][j][r] + bo[n];
      }
}

// ---------------------------------------------------------------------------
// Tree levels 1..6: block = 1 wave, owns (bh, 64-leaf group). Leaves staged in
// LDS via global_load_lds. Lane = column d. Binary-counter accumulation.
// grid = (64, 32)
// ---------------------------------------------------------------------------
__global__ __launch_bounds__(64) void tree_l16(bf16* __restrict__ fK, bf16* __restrict__ fV) {
  __shared__ __align__(16) bf16 Kl[64 * 64];
  __shared__ __align__(16) bf16 Vl[64 * 64];
  const int g = blockIdx.x, bh = blockIdx.y;
  const int lane = threadIdx.x;
  const size_t fb = (size_t)bh * NFLAT * 64;
  const size_t leafbase = fb + (size_t)g * 64 * 64;
#pragma unroll
  for (int it = 0; it < 8; it++) {
    glds16(fK + leafbase + it * 512 + lane * 8, Kl + it * 512);
    glds16(fV + leafbase + it * 512 + lane * 8, Vl + it * 512);
  }
  asm volatile("s_waitcnt vmcnt(0)" ::: "memory");
  __syncthreads();

  float pk[7], pv[7];
#pragma unroll
  for (int i = 0; i < 64; i++) {
    float ck = (float)Kl[i * 64 + lane];
    float cv = (float)Vl[i * 64 + lane];
#pragma unroll
    for (int l = 1; l <= 6; l++) {
      if (((i + 1) & ((1 << l) - 1)) != 0) { pk[l] = ck; pv[l] = cv; break; }
      ck += pk[l]; cv += pv[l];
      const int j = (g * 64 + i) >> l;
      fK[fb + (size_t)(off_l(l) + j) * 64 + lane] = (bf16)(ck * (1.0f / (1 << l)));
      fV[fb + (size_t)(off_l(l) + j) * 64 + lane] = (bf16)cv;
    }
  }
}

// ---------------------------------------------------------------------------
// Tree levels 7..12 from level 6. Block = 1 wave per bh, lane = column d.
// grid = 32
// ---------------------------------------------------------------------------
__global__ __launch_bounds__(64) void tree_l712(bf16* __restrict__ fK, bf16* __restrict__ fV) {
  __shared__ float Ks[64 * 64];
  __shared__ float Vs[64 * 64];
  const int bh = blockIdx.x, d = threadIdx.x;
  const size_t fb = (size_t)bh * NFLAT * 64;
#pragma unroll 8
  for (int i = 0; i < 64; i++) {
    Ks[i * 64 + d] = (float)fK[fb + (size_t)(8064 + i) * 64 + d];  // off_l(6)=8064
    Vs[i * 64 + d] = (float)fV[fb + (size_t)(8064 + i) * 64 + d];
  }
#pragma unroll
  for (int l = 7; l <= 12; l++) {
    const int cnt = 4096 >> l;   // 32,16,8,4,2,1
    for (int j = 0; j < cnt; j++) {
      const float k = (Ks[(2 * j) * 64 + d] + Ks[(2 * j + 1) * 64 + d]) * 0.5f;
      const float v =  Vs[(2 * j) * 64 + d] + Vs[(2 * j + 1) * 64 + d];
      Ks[j * 64 + d] = k;
      Vs[j * 64 + d] = v;
      fK[fb + (size_t)(off_l(l) + j) * 64 + d] = (bf16)k;
      fV[fb + (size_t)(off_l(l) + j) * 64 + d] = (bf16)v;
    }
  }
}

// ---------------------------------------------------------------------------
// Sparse attention: per token 13 candidates (self + levels 0..11).
//   neighbor flat idx at level l = OFF(l) + ((n>>l)^1); valid iff (n>>l)&1.
// Block = 1 wave = 64 consecutive tokens of one (b,h); 132 K/V rows in LDS
// (XOR-swizzled chunks). grid = (64, 32)
// ---------------------------------------------------------------------------
__global__ __launch_bounds__(64) void attn_kernel(
    const bf16* __restrict__ Qb, const bf16* __restrict__ fK,
    const bf16* __restrict__ fV, bf16* __restrict__ Ob) {
  __shared__ __align__(16) unsigned short Kl[132 * 64];
  __shared__ __align__(16) unsigned short Vl[132 * 64];
  const int t0  = blockIdx.x * 64;
  const int bh  = blockIdx.y;
  const int tid = threadIdx.x;
  const size_t fb = (size_t)bh * NFLAT * 64;

  for (int u = tid; u < 132 * 8; u += 64) {
    const int r = u >> 3, c = u & 7;
    int flat;
    if      (r < 64)  flat = t0 + r;
    else if (r < 96)  flat = 4096 + (t0 >> 1) + (r - 64);
    else if (r < 112) flat = 6144 + (t0 >> 2) + (r - 96);
    else if (r < 120) flat = 7168 + (t0 >> 3) + (r - 112);
    else if (r < 124) flat = 7680 + (t0 >> 4) + (r - 120);
    else if (r < 126) flat = 7936 + (t0 >> 5) + (r - 124);
    else { const int l = r - 120; flat = (8192 - (8192 >> l) + (t0 >> l)) ^ 1; }
    const int cc = c ^ (r & 7);
    const uint4 kk = *(const uint4*)((const char*)(fK + fb + (size_t)flat * 64) + c * 16);
    const uint4 vv = *(const uint4*)((const char*)(fV + fb + (size_t)flat * 64) + c * 16);
    *(uint4*)((char*)Kl + r * 128 + cc * 16) = kk;
    *(uint4*)((char*)Vl + r * 128 + cc * 16) = vv;
  }
  __syncthreads();

  const int n = t0 + tid;
  int rows[13];
  rows[0] = tid;
#pragma unroll
  for (int l = 0; l < 12; l++) {
    int r;
    if (l == 0)      r = tid ^ 1;
    else if (l <= 5) r = (128 - (128 >> l)) + (((n >> l) ^ 1) - (t0 >> l));
    else             r = 126 + (l - 6);
    rows[l + 1] = r;
  }

  float q[64];
  const bf16* Qr = Qb + ((size_t)bh * L_SEQ + n) * 64;
#pragma unroll
  for (int c = 0; c < 8; c++) {
    bf16x8 v = *(const bf16x8*)(Qr + c * 8);
#pragma unroll
    for (int j = 0; j < 8; j++) q[c * 8 + j] = (float)v[j];
  }

  float lg[13];
#pragma unroll
  for (int v = 0; v < 13; v++) {
    const int r = rows[v];
    float a = 0.f;
#pragma unroll
    for (int c = 0; c < 8; c++) {
      const int cc = c ^ (r & 7);
      const bf16x8 kv = *(const bf16x8*)((const char*)Kl + r * 128 + cc * 16);
#pragma unroll
      for (int j = 0; j < 8; j++) a += q[c * 8 + j] * (float)kv[j];
    }
    lg[v] = a * 0.125f;
  }
#pragma unroll
  for (int v = 1; v < 13; v++)
    if (!((n >> (v - 1)) & 1)) lg[v] = -1e30f;

  float mx = lg[0];
#pragma unroll
  for (int v = 1; v < 13; v++) mx = fmaxf(mx, lg[v]);
  float w[13], s = 0.f;
#pragma unroll
  for (int v = 0; v < 13; v++) { w[v] = __expf(lg[v] - mx); s += w[v]; }
  const float inv = 1.0f / s;

  float o[64];
#pragma unroll
  for (int d = 0; d < 64; d++) o[d] = 0.f;
#pragma unroll
  for (int v = 0; v < 13; v++) {
    const int r = rows[v];
    const float wv = w[v];
#pragma unroll
    for (int c = 0; c < 8; c++) {
      const int cc = c ^ (r & 7);
      const bf16x8 vv = *(const bf16x8*)((const char*)Vl + r * 128 + cc * 16);
#pragma unroll
      for (int j = 0; j < 8; j++) o[c * 8 + j] += wv * (float)vv[j];
    }
  }

  bf16* Or = Ob + ((size_t)(bh >> 4) * L_SEQ + n) * 1024 + (size_t)(bh & 15) * 64;
#pragma unroll
  for (int c = 0; c < 8; c++) {
    bf16x8 ov;
#pragma unroll
    for (int j = 0; j < 8; j++) ov[j] = (bf16)(o[c * 8 + j] * inv);
    *(bf16x8*)(Or + c * 8) = ov;
  }
}

// ---------------------------------------------------------------------------
extern "C" void kernel_launch(void* const* d_in, const int* in_sizes, int n_in,
                              void* d_out, int out_size, void* d_ws, size_t ws_size,
                              hipStream_t stream) {
  const float* query = (const float*)d_in[0];
  const float* key   = (const float*)d_in[1];
  const float* value = (const float*)d_in[2];
  const float* Wq    = (const float*)d_in[3];
  const float* Wk    = (const float*)d_in[4];
  const float* Wv    = (const float*)d_in[5];
  const float* Wo    = (const float*)d_in[6];
  const float* bo    = (const float*)d_in[7];
  float* out = (float*)d_out;

  char* ws = (char*)d_ws;
  size_t off = 0;
  auto take = [&](size_t bytes) -> void* {
    void* p = ws + off;
    off += (bytes + 255) & ~(size_t)255;
    return p;
  };
  const size_t XB = (size_t)8192 * 1024 * 2;   // 16.78 MB
  const size_t WB = (size_t)1024 * 1024 * 2;   //  2.10 MB
  bf16* qx  = (bf16*)take(XB);
  bf16* kx  = (bf16*)take(XB);
  bf16* vx  = (bf16*)take(XB);
  bf16* wqx = (bf16*)take(WB);
  bf16* wkx = (bf16*)take(WB);
  bf16* wvx = (bf16*)take(WB);
  bf16* wox = (bf16*)take(WB);
  bf16* Qb  = (bf16*)take((size_t)32 * L_SEQ * 64 * 2);   // 16.78 MB
  bf16* fK  = (bf16*)take((size_t)32 * NFLAT * 64 * 2);   // 33.55 MB
  bf16* fV  = (bf16*)take((size_t)32 * NFLAT * 64 * 2);   // 33.55 MB
  bf16* Ob  = qx;  // alias: qx's last read is gemm8_qkv; Ob first written by attn
  (void)in_sizes; (void)n_in; (void)out_size; (void)ws_size;

  // 1. fp32 -> bf16
  cvt3_kernel<<<dim3(8192, 3), 256, 0, stream>>>(query, key, value, qx, kx, vx);
  cvt4_kernel<<<dim3(1024, 4), 256, 0, stream>>>(Wq, Wk, Wv, Wo, wqx, wkx, wvx, wox);

  // 2. Q/K/V projections (8-phase GEMM)
  gemm8_qkv_kernel<<<dim3(256, 3), 512, 0, stream>>>(qx, kx, vx, wqx, wkx, wvx, Qb, fK, fV);

  // 3. hierarchy
  tree_l16 <<<dim3(64, 32), 64, 0, stream>>>(fK, fV);
  tree_l712<<<32, 64, 0, stream>>>(fK, fV);

  // 4. sparse attention
  attn_kernel<<<dim3(64, 32), 64, 0, stream>>>(Qb, fK, fV, Ob);

  // 5. output projection (8-phase GEMM)
  gemm8_out_kernel<<<256, 512, 0, stream>>>(Ob, wox, bo, out);
}

// Round 6
// 185.752 us; speedup vs baseline: 1.0678x; 1.0678x over previous
//
#include <hip/hip_runtime.h>
#include <cstdint>
#include <cstddef>

// ---------------------------------------------------------------------------
// HierarchicalSparseAttention  B=2 L=4096 D=1024 H=16 DH=64
// cvt(f32->bf16) -> QKV GEMM (256x128 3-ring counted-vmcnt bf16 MFMA) ->
// tree build -> sparse attn -> output GEMM (+bias, f32)
// ---------------------------------------------------------------------------

typedef __bf16 bf16;
typedef __bf16 bf16x8 __attribute__((ext_vector_type(8)));
typedef __bf16 bf16x4 __attribute__((ext_vector_type(4)));
typedef float  f32x4  __attribute__((ext_vector_type(4)));

#define L_SEQ  4096
#define NFLAT  8192   /* padded 2L-1 = 8191 */

__device__ __forceinline__ int off_l(int l) { return 8192 - (8192 >> l); }

// ---- async global->LDS, 16B per lane; lds base must be wave-uniform --------
__device__ __forceinline__ void glds16(const bf16* g, bf16* l) {
  __builtin_amdgcn_global_load_lds(
      (const __attribute__((address_space(1))) unsigned int*)g,
      (__attribute__((address_space(3))) unsigned int*)l, 16, 0, 0);
}

#define MEMFENCE asm volatile("" ::: "memory")
__device__ __forceinline__ void barrier_raw() {
  MEMFENCE; __builtin_amdgcn_s_barrier(); MEMFENCE;
}

// st_16x32 XOR swizzle (involution; permutes 16B chunks, preserves alignment)
__device__ __forceinline__ int swz(int b) { return b ^ (((b >> 9) & 1) << 5); }
// logical byte addr of (row, col) in a [R][64] bf16 tile stored as [16][32]
// subtiles (1024B each), 2 col-blocks per row-block
__device__ __forceinline__ int la(int row, int col) {
  return ((((row >> 4) << 1) + (col >> 5)) << 10) + ((row & 15) << 6) + ((col & 31) << 1);
}

// ---------------------------------------------------------------------------
// fp32 -> bf16 conversions (2 launches total)
// ---------------------------------------------------------------------------
__global__ __launch_bounds__(256) void cvt3_kernel(
    const float* __restrict__ a, const float* __restrict__ b, const float* __restrict__ c,
    bf16* __restrict__ x, bf16* __restrict__ y, bf16* __restrict__ z) {
  const int s = blockIdx.y;
  const float* src = (s == 0) ? a : (s == 1) ? b : c;
  bf16*        dst = (s == 0) ? x : (s == 1) ? y : z;
  const int i = blockIdx.x * 256 + threadIdx.x;   // < 2097152 by grid
  const float4 v = ((const float4*)src)[i];
  bf16x4 o;
  o[0] = (bf16)v.x; o[1] = (bf16)v.y; o[2] = (bf16)v.z; o[3] = (bf16)v.w;
  *(bf16x4*)(dst + (size_t)i * 4) = o;
}

__global__ __launch_bounds__(256) void cvt4_kernel(
    const float* __restrict__ a, const float* __restrict__ b,
    const float* __restrict__ c, const float* __restrict__ d,
    bf16* __restrict__ x, bf16* __restrict__ y, bf16* __restrict__ z, bf16* __restrict__ w) {
  const int s = blockIdx.y;
  const float* src = (s == 0) ? a : (s == 1) ? b : (s == 2) ? c : d;
  bf16*        dst = (s == 0) ? x : (s == 1) ? y : (s == 2) ? z : w;
  const int i = blockIdx.x * 256 + threadIdx.x;   // < 262144 by grid
  const float4 v = ((const float4*)src)[i];
  bf16x4 o;
  o[0] = (bf16)v.x; o[1] = (bf16)v.y; o[2] = (bf16)v.z; o[3] = (bf16)v.w;
  *(bf16x4*)(dst + (size_t)i * 4) = o;
}

// ---------------------------------------------------------------------------
// GEMM: C(256x128) = A(256xK) * W(128xK)^T, K=1024, BK=64, bf16 MFMA.
// 512 threads = 8 waves (4M x 2N); wave output 64x64 = 4x4 frags 16x16x32.
// 3-buffer LDS ring (48KB each), prefetch depth 2 tiles, counted vmcnt(6)
// (never drains mid-loop), one raw barrier per K-tile, setprio on MFMA.
// Staging: global_load_lds LINEAR dest + inverse-swizzled SOURCE (rule 21).
// ---------------------------------------------------------------------------
#define BUFB 49152   /* 32KB A + 16KB B */

__device__ __forceinline__ void stage_tile(const bf16* __restrict__ A,
                                           const bf16* __restrict__ W,
                                           int tm, int tn, int k0,
                                           char* buf, int tid, int wid) {
  bf16* Ad = (bf16*)buf;
  bf16* Bd = (bf16*)(buf + 32768);
  // A: 256x64 = 32KB = 4 rounds of 512thr x 16B
#pragma unroll
  for (int i = 0; i < 4; i++) {
    const int d  = i * 8192 + tid * 16;
    const int lb = swz(d);
    const int row = ((lb >> 10) >> 1) * 16 + ((lb >> 6) & 15);
    const int col = ((lb >> 10) & 1) * 32 + ((lb & 63) >> 1);
    glds16(A + (size_t)(tm * 256 + row) * 1024 + k0 + col, Ad + (i * 8192 + wid * 1024) / 2);
  }
  // B: 128x64 = 16KB = 2 rounds
#pragma unroll
  for (int i = 0; i < 2; i++) {
    const int d  = i * 8192 + tid * 16;
    const int lb = swz(d);
    const int row = ((lb >> 10) >> 1) * 16 + ((lb >> 6) & 15);
    const int col = ((lb >> 10) & 1) * 32 + ((lb & 63) >> 1);
    glds16(W + (size_t)(tn * 128 + row) * 1024 + k0 + col, Bd + (i * 8192 + wid * 1024) / 2);
  }
}

__device__ __forceinline__ void gemm8_core(const bf16* __restrict__ A,
                                           const bf16* __restrict__ W,
                                           int tm, int tn, char* lds,
                                           f32x4 (&acc)[4][4]) {
  const int tid  = threadIdx.x;
  const int wid  = tid >> 6, lane = tid & 63;
  const int wm   = wid >> 1, wn = wid & 1;
  const int laneR  = lane & 15;
  const int laneC8 = (lane >> 4) * 8;

  char* b0 = lds;              // tile u
  char* b1 = lds + BUFB;       // tile u+1
  char* b2 = lds + 2 * BUFB;   // tile u+2 (staged this iter; freed u-1)

  stage_tile(A, W, tm, tn, 0,  b0, tid, wid);   // 6 loads
  stage_tile(A, W, tm, tn, 64, b1, tid, wid);   // +6 = 12 in flight

  for (int u = 0; u < 16; ++u) {
    // counted wait: stage(u) done; stage(u+1) (6 loads) stays in flight.
    if (u < 15) asm volatile("s_waitcnt vmcnt(6)" ::: "memory");
    else        asm volatile("s_waitcnt vmcnt(0)" ::: "memory");
    barrier_raw();   // all waves' stage(u) visible; all tile u-1 reads consumed
    // prefetch tile u+2 into freed buffer (b2 held tile u-1)
    if (u + 2 < 16) stage_tile(A, W, tm, tn, (u + 2) << 6, b2, tid, wid);

    const char* Ab = b0;
    const char* Bb = b0 + 32768;
    bf16x8 af[4][2], bfr[4][2];
#pragma unroll
    for (int f = 0; f < 4; f++)
#pragma unroll
      for (int ks = 0; ks < 2; ks++)
        af[f][ks] = *(const bf16x8*)(Ab + swz(la(wm * 64 + f * 16 + laneR, ks * 32 + laneC8)));
#pragma unroll
    for (int j = 0; j < 4; j++)
#pragma unroll
      for (int ks = 0; ks < 2; ks++)
        bfr[j][ks] = *(const bf16x8*)(Bb + swz(la(wn * 64 + j * 16 + laneR, ks * 32 + laneC8)));

    __builtin_amdgcn_s_setprio(1);
#pragma unroll
    for (int f = 0; f < 4; f++)
#pragma unroll
      for (int j = 0; j < 4; j++)
#pragma unroll
        for (int ks = 0; ks < 2; ks++)
          acc[f][j] = __builtin_amdgcn_mfma_f32_16x16x32_bf16(
              af[f][ks], bfr[j][ks], acc[f][j], 0, 0, 0);
    __builtin_amdgcn_s_setprio(0);

    char* t = b0; b0 = b1; b1 = b2; b2 = t;   // rotate ring
  }
}

// QKV projections. grid = (256, 3): tm = x>>3, tn = x&7; y -> {Q,K,V}.
// Writes Q -> [bh][l][64], K/V -> flat level-0 [bh][node][64].
__global__ __launch_bounds__(512, 2) void gemm8_qkv_kernel(
    const bf16* __restrict__ qx, const bf16* __restrict__ kx, const bf16* __restrict__ vx,
    const bf16* __restrict__ wq, const bf16* __restrict__ wk, const bf16* __restrict__ wv,
    bf16* __restrict__ Qb, bf16* __restrict__ fK, bf16* __restrict__ fV) {
  __shared__ __align__(16) char lds[3 * BUFB];
  const int z = blockIdx.y;
  const bf16* A = (z == 0) ? qx : (z == 1) ? kx : vx;
  const bf16* W = (z == 0) ? wq : (z == 1) ? wk : wv;
  bf16* D       = (z == 0) ? Qb : (z == 1) ? fK : fV;
  const int lstr = (z == 0) ? L_SEQ : NFLAT;
  const int tm = blockIdx.x >> 3, tn = blockIdx.x & 7;
  f32x4 acc[4][4] = {};
  gemm8_core(A, W, tm, tn, lds, acc);
  const int lane = threadIdx.x & 63, wid = threadIdx.x >> 6;
  const int m0 = tm * 256 + (wid >> 1) * 64 + (lane >> 4) * 4;
  const int n0 = tn * 128 + (wid & 1) * 64 + (lane & 15);
#pragma unroll
  for (int i = 0; i < 4; i++)
#pragma unroll
    for (int j = 0; j < 4; j++)
#pragma unroll
      for (int r = 0; r < 4; r++) {
        const int m = m0 + i * 16 + r;
        const int n = n0 + j * 16;
        const int b = m >> 12, l = m & 4095;
        const int h = n >> 6,  dh = n & 63;
        D[((size_t)(b * 16 + h) * lstr + l) * 64 + dh] = (bf16)acc[i][j][r];
      }
}

// Output projection + bias, f32 out (8192 x 1024). grid = 256.
__global__ __launch_bounds__(512, 2) void gemm8_out_kernel(
    const bf16* __restrict__ Ob, const bf16* __restrict__ wo,
    const float* __restrict__ bo, float* __restrict__ out) {
  __shared__ __align__(16) char lds[3 * BUFB];
  const int tm = blockIdx.x >> 3, tn = blockIdx.x & 7;
  f32x4 acc[4][4] = {};
  gemm8_core(Ob, wo, tm, tn, lds, acc);
  const int lane = threadIdx.x & 63, wid = threadIdx.x >> 6;
  const int m0 = tm * 256 + (wid >> 1) * 64 + (lane >> 4) * 4;
  const int n0 = tn * 128 + (wid & 1) * 64 + (lane & 15);
#pragma unroll
  for (int i = 0; i < 4; i++)
#pragma unroll
    for (int j = 0; j < 4; j++)
#pragma unroll
      for (int r = 0; r < 4; r++) {
        const int m = m0 + i * 16 + r;
        const int n = n0 + j * 16;
        out[(size_t)m * 1024 + n] = acc[i][j][r] + bo[n];
      }
}

// ---------------------------------------------------------------------------
// Tree levels 1..6: block = 1 wave, owns (bh, 64-leaf group). Leaves staged in
// LDS via global_load_lds. Lane = column d. Binary-counter accumulation.
// grid = (64, 32)
// ---------------------------------------------------------------------------
__global__ __launch_bounds__(64) void tree_l16(bf16* __restrict__ fK, bf16* __restrict__ fV) {
  __shared__ __align__(16) bf16 Kl[64 * 64];
  __shared__ __align__(16) bf16 Vl[64 * 64];
  const int g = blockIdx.x, bh = blockIdx.y;
  const int lane = threadIdx.x;
  const size_t fb = (size_t)bh * NFLAT * 64;
  const size_t leafbase = fb + (size_t)g * 64 * 64;
#pragma unroll
  for (int it = 0; it < 8; it++) {
    glds16(fK + leafbase + it * 512 + lane * 8, Kl + it * 512);
    glds16(fV + leafbase + it * 512 + lane * 8, Vl + it * 512);
  }
  asm volatile("s_waitcnt vmcnt(0)" ::: "memory");
  __syncthreads();

  float pk[7], pv[7];
#pragma unroll
  for (int i = 0; i < 64; i++) {
    float ck = (float)Kl[i * 64 + lane];
    float cv = (float)Vl[i * 64 + lane];
#pragma unroll
    for (int l = 1; l <= 6; l++) {
      if (((i + 1) & ((1 << l) - 1)) != 0) { pk[l] = ck; pv[l] = cv; break; }
      ck += pk[l]; cv += pv[l];
      const int j = (g * 64 + i) >> l;
      fK[fb + (size_t)(off_l(l) + j) * 64 + lane] = (bf16)(ck * (1.0f / (1 << l)));
      fV[fb + (size_t)(off_l(l) + j) * 64 + lane] = (bf16)cv;
    }
  }
}

// ---------------------------------------------------------------------------
// Tree levels 7..12 from level 6. Block = 1 wave per bh, lane = column d.
// grid = 32
// ---------------------------------------------------------------------------
__global__ __launch_bounds__(64) void tree_l712(bf16* __restrict__ fK, bf16* __restrict__ fV) {
  __shared__ float Ks[64 * 64];
  __shared__ float Vs[64 * 64];
  const int bh = blockIdx.x, d = threadIdx.x;
  const size_t fb = (size_t)bh * NFLAT * 64;
#pragma unroll 8
  for (int i = 0; i < 64; i++) {
    Ks[i * 64 + d] = (float)fK[fb + (size_t)(8064 + i) * 64 + d];  // off_l(6)=8064
    Vs[i * 64 + d] = (float)fV[fb + (size_t)(8064 + i) * 64 + d];
  }
#pragma unroll
  for (int l = 7; l <= 12; l++) {
    const int cnt = 4096 >> l;   // 32,16,8,4,2,1
    for (int j = 0; j < cnt; j++) {
      const float k = (Ks[(2 * j) * 64 + d] + Ks[(2 * j + 1) * 64 + d]) * 0.5f;
      const float v =  Vs[(2 * j) * 64 + d] + Vs[(2 * j + 1) * 64 + d];
      Ks[j * 64 + d] = k;
      Vs[j * 64 + d] = v;
      fK[fb + (size_t)(off_l(l) + j) * 64 + d] = (bf16)k;
      fV[fb + (size_t)(off_l(l) + j) * 64 + d] = (bf16)v;
    }
  }
}

// ---------------------------------------------------------------------------
// Sparse attention: per token 13 candidates (self + levels 0..11).
//   neighbor flat idx at level l = OFF(l) + ((n>>l)^1); valid iff (n>>l)&1.
// Block = 1 wave = 64 consecutive tokens of one (b,h); 132 K/V rows in LDS
// (XOR-swizzled chunks). grid = (64, 32)
// ---------------------------------------------------------------------------
__global__ __launch_bounds__(64) void attn_kernel(
    const bf16* __restrict__ Qb, const bf16* __restrict__ fK,
    const bf16* __restrict__ fV, bf16* __restrict__ Ob) {
  __shared__ __align__(16) unsigned short Kl[132 * 64];
  __shared__ __align__(16) unsigned short Vl[132 * 64];
  const int t0  = blockIdx.x * 64;
  const int bh  = blockIdx.y;
  const int tid = threadIdx.x;
  const size_t fb = (size_t)bh * NFLAT * 64;

  for (int u = tid; u < 132 * 8; u += 64) {
    const int r = u >> 3, c = u & 7;
    int flat;
    if      (r < 64)  flat = t0 + r;
    else if (r < 96)  flat = 4096 + (t0 >> 1) + (r - 64);
    else if (r < 112) flat = 6144 + (t0 >> 2) + (r - 96);
    else if (r < 120) flat = 7168 + (t0 >> 3) + (r - 112);
    else if (r < 124) flat = 7680 + (t0 >> 4) + (r - 120);
    else if (r < 126) flat = 7936 + (t0 >> 5) + (r - 124);
    else { const int l = r - 120; flat = (8192 - (8192 >> l) + (t0 >> l)) ^ 1; }
    const int cc = c ^ (r & 7);
    const uint4 kk = *(const uint4*)((const char*)(fK + fb + (size_t)flat * 64) + c * 16);
    const uint4 vv = *(const uint4*)((const char*)(fV + fb + (size_t)flat * 64) + c * 16);
    *(uint4*)((char*)Kl + r * 128 + cc * 16) = kk;
    *(uint4*)((char*)Vl + r * 128 + cc * 16) = vv;
  }
  __syncthreads();

  const int n = t0 + tid;
  int rows[13];
  rows[0] = tid;
#pragma unroll
  for (int l = 0; l < 12; l++) {
    int r;
    if (l == 0)      r = tid ^ 1;
    else if (l <= 5) r = (128 - (128 >> l)) + (((n >> l) ^ 1) - (t0 >> l));
    else             r = 126 + (l - 6);
    rows[l + 1] = r;
  }

  float q[64];
  const bf16* Qr = Qb + ((size_t)bh * L_SEQ + n) * 64;
#pragma unroll
  for (int c = 0; c < 8; c++) {
    bf16x8 v = *(const bf16x8*)(Qr + c * 8);
#pragma unroll
    for (int j = 0; j < 8; j++) q[c * 8 + j] = (float)v[j];
  }

  float lg[13];
#pragma unroll
  for (int v = 0; v < 13; v++) {
    const int r = rows[v];
    float a = 0.f;
#pragma unroll
    for (int c = 0; c < 8; c++) {
      const int cc = c ^ (r & 7);
      const bf16x8 kv = *(const bf16x8*)((const char*)Kl + r * 128 + cc * 16);
#pragma unroll
      for (int j = 0; j < 8; j++) a += q[c * 8 + j] * (float)kv[j];
    }
    lg[v] = a * 0.125f;
  }
#pragma unroll
  for (int v = 1; v < 13; v++)
    if (!((n >> (v - 1)) & 1)) lg[v] = -1e30f;

  float mx = lg[0];
#pragma unroll
  for (int v = 1; v < 13; v++) mx = fmaxf(mx, lg[v]);
  float w[13], s = 0.f;
#pragma unroll
  for (int v = 0; v < 13; v++) { w[v] = __expf(lg[v] - mx); s += w[v]; }
  const float inv = 1.0f / s;

  float o[64];
#pragma unroll
  for (int d = 0; d < 64; d++) o[d] = 0.f;
#pragma unroll
  for (int v = 0; v < 13; v++) {
    const int r = rows[v];
    const float wv = w[v];
#pragma unroll
    for (int c = 0; c < 8; c++) {
      const int cc = c ^ (r & 7);
      const bf16x8 vv = *(const bf16x8*)((const char*)Vl + r * 128 + cc * 16);
#pragma unroll
      for (int j = 0; j < 8; j++) o[c * 8 + j] += wv * (float)vv[j];
    }
  }

  bf16* Or = Ob + ((size_t)(bh >> 4) * L_SEQ + n) * 1024 + (size_t)(bh & 15) * 64;
#pragma unroll
  for (int c = 0; c < 8; c++) {
    bf16x8 ov;
#pragma unroll
    for (int j = 0; j < 8; j++) ov[j] = (bf16)(o[c * 8 + j] * inv);
    *(bf16x8*)(Or + c * 8) = ov;
  }
}

// ---------------------------------------------------------------------------
extern "C" void kernel_launch(void* const* d_in, const int* in_sizes, int n_in,
                              void* d_out, int out_size, void* d_ws, size_t ws_size,
                              hipStream_t stream) {
  const float* query = (const float*)d_in[0];
  const float* key   = (const float*)d_in[1];
  const float* value = (const float*)d_in[2];
  const float* Wq    = (const float*)d_in[3];
  const float* Wk    = (const float*)d_in[4];
  const float* Wv    = (const float*)d_in[5];
  const float* Wo    = (const float*)d_in[6];
  const float* bo    = (const float*)d_in[7];
  float* out = (float*)d_out;

  char* ws = (char*)d_ws;
  size_t off = 0;
  auto take = [&](size_t bytes) -> void* {
    void* p = ws + off;
    off += (bytes + 255) & ~(size_t)255;
    return p;
  };
  const size_t XB = (size_t)8192 * 1024 * 2;   // 16.78 MB
  const size_t WB = (size_t)1024 * 1024 * 2;   //  2.10 MB
  bf16* qx  = (bf16*)take(XB);
  bf16* kx  = (bf16*)take(XB);
  bf16* vx  = (bf16*)take(XB);
  bf16* wqx = (bf16*)take(WB);
  bf16* wkx = (bf16*)take(WB);
  bf16* wvx = (bf16*)take(WB);
  bf16* wox = (bf16*)take(WB);
  bf16* Qb  = (bf16*)take((size_t)32 * L_SEQ * 64 * 2);   // 16.78 MB
  bf16* fK  = (bf16*)take((size_t)32 * NFLAT * 64 * 2);   // 33.55 MB
  bf16* fV  = (bf16*)take((size_t)32 * NFLAT * 64 * 2);   // 33.55 MB
  bf16* Ob  = qx;  // alias: qx's last read is gemm8_qkv; Ob first written by attn
  (void)in_sizes; (void)n_in; (void)out_size; (void)ws_size;

  // 1. fp32 -> bf16
  cvt3_kernel<<<dim3(8192, 3), 256, 0, stream>>>(query, key, value, qx, kx, vx);
  cvt4_kernel<<<dim3(1024, 4), 256, 0, stream>>>(Wq, Wk, Wv, Wo, wqx, wkx, wvx, wox);

  // 2. Q/K/V projections (3-ring counted-vmcnt GEMM)
  gemm8_qkv_kernel<<<dim3(256, 3), 512, 0, stream>>>(qx, kx, vx, wqx, wkx, wvx, Qb, fK, fV);

  // 3. hierarchy
  tree_l16 <<<dim3(64, 32), 64, 0, stream>>>(fK, fV);
  tree_l712<<<32, 64, 0, stream>>>(fK, fV);

  // 4. sparse attention
  attn_kernel<<<dim3(64, 32), 64, 0, stream>>>(Qb, fK, fV, Ob);

  // 5. output projection (3-ring counted-vmcnt GEMM)
  gemm8_out_kernel<<<256, 512, 0, stream>>>(Ob, wox, bo, out);
}

// Round 7
// 165.266 us; speedup vs baseline: 1.2001x; 1.1240x over previous
//
#include <hip/hip_runtime.h>
#include <cstdint>
#include <cstddef>

// ---------------------------------------------------------------------------
// HierarchicalSparseAttention  B=2 L=4096 D=1024 H=16 DH=64
// cvt(f32->bf16) -> QKV GEMM (128x128 2-ring, XCD-chunked) -> tree build ->
// sparse attn -> output GEMM (+bias, f32)
// ---------------------------------------------------------------------------

typedef __bf16 bf16;
typedef __bf16 bf16x8 __attribute__((ext_vector_type(8)));
typedef __bf16 bf16x4 __attribute__((ext_vector_type(4)));
typedef float  f32x4  __attribute__((ext_vector_type(4)));

#define L_SEQ  4096
#define NFLAT  8192   /* padded 2L-1 = 8191 */

__device__ __forceinline__ int off_l(int l) { return 8192 - (8192 >> l); }

// ---- async global->LDS, 16B per lane; lds base must be wave-uniform --------
__device__ __forceinline__ void glds16(const bf16* g, bf16* l) {
  __builtin_amdgcn_global_load_lds(
      (const __attribute__((address_space(1))) unsigned int*)g,
      (__attribute__((address_space(3))) unsigned int*)l, 16, 0, 0);
}

#define MEMFENCE asm volatile("" ::: "memory")
__device__ __forceinline__ void barrier_raw() {
  MEMFENCE; __builtin_amdgcn_s_barrier(); MEMFENCE;
}

// st_16x32 XOR swizzle (involution; permutes 16B chunks, preserves alignment)
__device__ __forceinline__ int swz(int b) { return b ^ (((b >> 9) & 1) << 5); }
// logical byte addr of (row, col) in a [R][64] bf16 tile stored as [16][32]
// subtiles (1024B each), 2 col-blocks per row-block
__device__ __forceinline__ int la(int row, int col) {
  return ((((row >> 4) << 1) + (col >> 5)) << 10) + ((row & 15) << 6) + ((col & 31) << 1);
}

// ---------------------------------------------------------------------------
// fp32 -> bf16 conversions (2 launches total)
// ---------------------------------------------------------------------------
__global__ __launch_bounds__(256) void cvt3_kernel(
    const float* __restrict__ a, const float* __restrict__ b, const float* __restrict__ c,
    bf16* __restrict__ x, bf16* __restrict__ y, bf16* __restrict__ z) {
  const int s = blockIdx.y;
  const float* src = (s == 0) ? a : (s == 1) ? b : c;
  bf16*        dst = (s == 0) ? x : (s == 1) ? y : z;
  const int i = blockIdx.x * 256 + threadIdx.x;   // < 2097152 by grid
  const float4 v = ((const float4*)src)[i];
  bf16x4 o;
  o[0] = (bf16)v.x; o[1] = (bf16)v.y; o[2] = (bf16)v.z; o[3] = (bf16)v.w;
  *(bf16x4*)(dst + (size_t)i * 4) = o;
}

__global__ __launch_bounds__(256) void cvt4_kernel(
    const float* __restrict__ a, const float* __restrict__ b,
    const float* __restrict__ c, const float* __restrict__ d,
    bf16* __restrict__ x, bf16* __restrict__ y, bf16* __restrict__ z, bf16* __restrict__ w) {
  const int s = blockIdx.y;
  const float* src = (s == 0) ? a : (s == 1) ? b : (s == 2) ? c : d;
  bf16*        dst = (s == 0) ? x : (s == 1) ? y : (s == 2) ? z : w;
  const int i = blockIdx.x * 256 + threadIdx.x;   // < 262144 by grid
  const float4 v = ((const float4*)src)[i];
  bf16x4 o;
  o[0] = (bf16)v.x; o[1] = (bf16)v.y; o[2] = (bf16)v.z; o[3] = (bf16)v.w;
  *(bf16x4*)(dst + (size_t)i * 4) = o;
}

// ---------------------------------------------------------------------------
// GEMM: C(128x128) = A(128xK) * W(128xK)^T, K=1024, BK=64, bf16 MFMA.
// 256 threads = 4 waves (2M x 2N); wave output 64x64 = 4x4 frags 16x16x32.
// 2-buffer LDS ring (32KB each -> 64KB total -> 2 blocks/CU), depth-1
// prefetch (stage(u+1) in flight across iter u's compute), swizzled LDS,
// one raw barrier per K-tile, setprio on MFMA.
// Staging: global_load_lds LINEAR dest + inverse-swizzled SOURCE (rule 21).
// ---------------------------------------------------------------------------
#define BUFB 32768   /* 16KB A + 16KB B */

__device__ __forceinline__ void stage_tile(const bf16* __restrict__ A,
                                           const bf16* __restrict__ W,
                                           int tm, int tn, int k0,
                                           char* buf, int tid, int wid) {
  bf16* Ad = (bf16*)buf;
  bf16* Bd = (bf16*)(buf + 16384);
  // A: 128x64 = 16KB = 4 rounds of 256thr x 16B;  B same
#pragma unroll
  for (int i = 0; i < 4; i++) {
    const int d  = i * 4096 + tid * 16;
    const int lb = swz(d);
    const int row = ((lb >> 10) >> 1) * 16 + ((lb >> 6) & 15);
    const int col = ((lb >> 10) & 1) * 32 + ((lb & 63) >> 1);
    glds16(A + (size_t)(tm * 128 + row) * 1024 + k0 + col, Ad + ((i * 4096 + wid * 1024) >> 1));
    glds16(W + (size_t)(tn * 128 + row) * 1024 + k0 + col, Bd + ((i * 4096 + wid * 1024) >> 1));
  }
}

__device__ __forceinline__ void gemm8_core(const bf16* __restrict__ A,
                                           const bf16* __restrict__ W,
                                           int tm, int tn, char* lds,
                                           f32x4 (&acc)[4][4]) {
  const int tid  = threadIdx.x;
  const int wid  = tid >> 6, lane = tid & 63;
  const int wm   = wid >> 1, wn = wid & 1;
  const int laneR  = lane & 15;
  const int laneC8 = (lane >> 4) * 8;

  stage_tile(A, W, tm, tn, 0, lds, tid, wid);   // tile 0 -> buf 0

  for (int u = 0; u < 16; ++u) {
    // stage(u) was issued one full iteration ago (prologue for u=0):
    // its latency is hidden under iter u-1's compute + the sibling block.
    asm volatile("s_waitcnt vmcnt(0)" ::: "memory");
    barrier_raw();   // stage(u) visible to all; buf[(u+1)&1] fully consumed
    if (u + 1 < 16)
      stage_tile(A, W, tm, tn, (u + 1) << 6, lds + ((u + 1) & 1) * BUFB, tid, wid);

    const char* Ab = lds + (u & 1) * BUFB;
    const char* Bb = Ab + 16384;
    bf16x8 af[4][2], bfr[4][2];
#pragma unroll
    for (int f = 0; f < 4; f++)
#pragma unroll
      for (int ks = 0; ks < 2; ks++)
        af[f][ks] = *(const bf16x8*)(Ab + swz(la(wm * 64 + f * 16 + laneR, ks * 32 + laneC8)));
#pragma unroll
    for (int j = 0; j < 4; j++)
#pragma unroll
      for (int ks = 0; ks < 2; ks++)
        bfr[j][ks] = *(const bf16x8*)(Bb + swz(la(wn * 64 + j * 16 + laneR, ks * 32 + laneC8)));

    __builtin_amdgcn_s_setprio(1);
#pragma unroll
    for (int f = 0; f < 4; f++)
#pragma unroll
      for (int j = 0; j < 4; j++)
#pragma unroll
        for (int ks = 0; ks < 2; ks++)
          acc[f][j] = __builtin_amdgcn_mfma_f32_16x16x32_bf16(
              af[f][ks], bfr[j][ks], acc[f][j], 0, 0, 0);
    __builtin_amdgcn_s_setprio(0);
  }
}

// XCD-chunked bijective tile map (512 blocks/z, 8 XCDs, round-robin xcd=bid&7):
// XCD x owns tm in [8x, 8x+8) for all tn -> A-panels fetched once per XCD,
// per-XCD working set = 2MB A-panels + 2MB W = L2-resident.
__device__ __forceinline__ void tile_map(int bid, int& tm, int& tn) {
  const int xcd = bid & 7, q = bid >> 3;
  tm = xcd * 8 + (q >> 3);
  tn = q & 7;
}

// QKV projections. grid = (512, 3). Writes Q -> [bh][l][64], K/V -> flat lvl-0.
__global__ __launch_bounds__(256, 2) void gemm8_qkv_kernel(
    const bf16* __restrict__ qx, const bf16* __restrict__ kx, const bf16* __restrict__ vx,
    const bf16* __restrict__ wq, const bf16* __restrict__ wk, const bf16* __restrict__ wv,
    bf16* __restrict__ Qb, bf16* __restrict__ fK, bf16* __restrict__ fV) {
  __shared__ __align__(16) char lds[2 * BUFB];
  const int z = blockIdx.y;
  const bf16* A = (z == 0) ? qx : (z == 1) ? kx : vx;
  const bf16* W = (z == 0) ? wq : (z == 1) ? wk : wv;
  bf16* D       = (z == 0) ? Qb : (z == 1) ? fK : fV;
  const int lstr = (z == 0) ? L_SEQ : NFLAT;
  int tm, tn; tile_map(blockIdx.x, tm, tn);
  f32x4 acc[4][4] = {};
  gemm8_core(A, W, tm, tn, lds, acc);
  const int lane = threadIdx.x & 63, wid = threadIdx.x >> 6;
  const int m0 = tm * 128 + (wid >> 1) * 64 + (lane >> 4) * 4;
  const int n0 = tn * 128 + (wid & 1) * 64 + (lane & 15);
#pragma unroll
  for (int i = 0; i < 4; i++)
#pragma unroll
    for (int j = 0; j < 4; j++)
#pragma unroll
      for (int r = 0; r < 4; r++) {
        const int m = m0 + i * 16 + r;
        const int n = n0 + j * 16;
        const int b = m >> 12, l = m & 4095;
        const int h = n >> 6,  dh = n & 63;
        D[((size_t)(b * 16 + h) * lstr + l) * 64 + dh] = (bf16)acc[i][j][r];
      }
}

// Output projection + bias, f32 out (8192 x 1024). grid = 512.
__global__ __launch_bounds__(256, 2) void gemm8_out_kernel(
    const bf16* __restrict__ Ob, const bf16* __restrict__ wo,
    const float* __restrict__ bo, float* __restrict__ out) {
  __shared__ __align__(16) char lds[2 * BUFB];
  int tm, tn; tile_map(blockIdx.x, tm, tn);
  f32x4 acc[4][4] = {};
  gemm8_core(Ob, wo, tm, tn, lds, acc);
  const int lane = threadIdx.x & 63, wid = threadIdx.x >> 6;
  const int m0 = tm * 128 + (wid >> 1) * 64 + (lane >> 4) * 4;
  const int n0 = tn * 128 + (wid & 1) * 64 + (lane & 15);
#pragma unroll
  for (int i = 0; i < 4; i++)
#pragma unroll
    for (int j = 0; j < 4; j++)
#pragma unroll
      for (int r = 0; r < 4; r++) {
        const int m = m0 + i * 16 + r;
        const int n = n0 + j * 16;
        out[(size_t)m * 1024 + n] = acc[i][j][r] + bo[n];
      }
}

// ---------------------------------------------------------------------------
// Tree levels 1..6: block = 1 wave, owns (bh, 64-leaf group). Leaves staged in
// LDS via global_load_lds. Lane = column d. Binary-counter accumulation.
// grid = (64, 32)
// ---------------------------------------------------------------------------
__global__ __launch_bounds__(64) void tree_l16(bf16* __restrict__ fK, bf16* __restrict__ fV) {
  __shared__ __align__(16) bf16 Kl[64 * 64];
  __shared__ __align__(16) bf16 Vl[64 * 64];
  const int g = blockIdx.x, bh = blockIdx.y;
  const int lane = threadIdx.x;
  const size_t fb = (size_t)bh * NFLAT * 64;
  const size_t leafbase = fb + (size_t)g * 64 * 64;
#pragma unroll
  for (int it = 0; it < 8; it++) {
    glds16(fK + leafbase + it * 512 + lane * 8, Kl + it * 512);
    glds16(fV + leafbase + it * 512 + lane * 8, Vl + it * 512);
  }
  asm volatile("s_waitcnt vmcnt(0)" ::: "memory");
  __syncthreads();

  float pk[7], pv[7];
#pragma unroll
  for (int i = 0; i < 64; i++) {
    float ck = (float)Kl[i * 64 + lane];
    float cv = (float)Vl[i * 64 + lane];
#pragma unroll
    for (int l = 1; l <= 6; l++) {
      if (((i + 1) & ((1 << l) - 1)) != 0) { pk[l] = ck; pv[l] = cv; break; }
      ck += pk[l]; cv += pv[l];
      const int j = (g * 64 + i) >> l;
      fK[fb + (size_t)(off_l(l) + j) * 64 + lane] = (bf16)(ck * (1.0f / (1 << l)));
      fV[fb + (size_t)(off_l(l) + j) * 64 + lane] = (bf16)cv;
    }
  }
}

// ---------------------------------------------------------------------------
// Tree levels 7..12 from level 6. Block = 1 wave per bh, lane = column d.
// grid = 32
// ---------------------------------------------------------------------------
__global__ __launch_bounds__(64) void tree_l712(bf16* __restrict__ fK, bf16* __restrict__ fV) {
  __shared__ float Ks[64 * 64];
  __shared__ float Vs[64 * 64];
  const int bh = blockIdx.x, d = threadIdx.x;
  const size_t fb = (size_t)bh * NFLAT * 64;
#pragma unroll 8
  for (int i = 0; i < 64; i++) {
    Ks[i * 64 + d] = (float)fK[fb + (size_t)(8064 + i) * 64 + d];  // off_l(6)=8064
    Vs[i * 64 + d] = (float)fV[fb + (size_t)(8064 + i) * 64 + d];
  }
#pragma unroll
  for (int l = 7; l <= 12; l++) {
    const int cnt = 4096 >> l;   // 32,16,8,4,2,1
    for (int j = 0; j < cnt; j++) {
      const float k = (Ks[(2 * j) * 64 + d] + Ks[(2 * j + 1) * 64 + d]) * 0.5f;
      const float v =  Vs[(2 * j) * 64 + d] + Vs[(2 * j + 1) * 64 + d];
      Ks[j * 64 + d] = k;
      Vs[j * 64 + d] = v;
      fK[fb + (size_t)(off_l(l) + j) * 64 + d] = (bf16)k;
      fV[fb + (size_t)(off_l(l) + j) * 64 + d] = (bf16)v;
    }
  }
}

// ---------------------------------------------------------------------------
// Sparse attention: per token 13 candidates (self + levels 0..11).
//   neighbor flat idx at level l = OFF(l) + ((n>>l)^1); valid iff (n>>l)&1.
// Block = 1 wave = 64 consecutive tokens of one (b,h); 132 K/V rows in LDS
// (XOR-swizzled chunks). grid = (64, 32)
// ---------------------------------------------------------------------------
__global__ __launch_bounds__(64) void attn_kernel(
    const bf16* __restrict__ Qb, const bf16* __restrict__ fK,
    const bf16* __restrict__ fV, bf16* __restrict__ Ob) {
  __shared__ __align__(16) unsigned short Kl[132 * 64];
  __shared__ __align__(16) unsigned short Vl[132 * 64];
  const int t0  = blockIdx.x * 64;
  const int bh  = blockIdx.y;
  const int tid = threadIdx.x;
  const size_t fb = (size_t)bh * NFLAT * 64;

  for (int u = tid; u < 132 * 8; u += 64) {
    const int r = u >> 3, c = u & 7;
    int flat;
    if      (r < 64)  flat = t0 + r;
    else if (r < 96)  flat = 4096 + (t0 >> 1) + (r - 64);
    else if (r < 112) flat = 6144 + (t0 >> 2) + (r - 96);
    else if (r < 120) flat = 7168 + (t0 >> 3) + (r - 112);
    else if (r < 124) flat = 7680 + (t0 >> 4) + (r - 120);
    else if (r < 126) flat = 7936 + (t0 >> 5) + (r - 124);
    else { const int l = r - 120; flat = (8192 - (8192 >> l) + (t0 >> l)) ^ 1; }
    const int cc = c ^ (r & 7);
    const uint4 kk = *(const uint4*)((const char*)(fK + fb + (size_t)flat * 64) + c * 16);
    const uint4 vv = *(const uint4*)((const char*)(fV + fb + (size_t)flat * 64) + c * 16);
    *(uint4*)((char*)Kl + r * 128 + cc * 16) = kk;
    *(uint4*)((char*)Vl + r * 128 + cc * 16) = vv;
  }
  __syncthreads();

  const int n = t0 + tid;
  int rows[13];
  rows[0] = tid;
#pragma unroll
  for (int l = 0; l < 12; l++) {
    int r;
    if (l == 0)      r = tid ^ 1;
    else if (l <= 5) r = (128 - (128 >> l)) + (((n >> l) ^ 1) - (t0 >> l));
    else             r = 126 + (l - 6);
    rows[l + 1] = r;
  }

  float q[64];
  const bf16* Qr = Qb + ((size_t)bh * L_SEQ + n) * 64;
#pragma unroll
  for (int c = 0; c < 8; c++) {
    bf16x8 v = *(const bf16x8*)(Qr + c * 8);
#pragma unroll
    for (int j = 0; j < 8; j++) q[c * 8 + j] = (float)v[j];
  }

  float lg[13];
#pragma unroll
  for (int v = 0; v < 13; v++) {
    const int r = rows[v];
    float a = 0.f;
#pragma unroll
    for (int c = 0; c < 8; c++) {
      const int cc = c ^ (r & 7);
      const bf16x8 kv = *(const bf16x8*)((const char*)Kl + r * 128 + cc * 16);
#pragma unroll
      for (int j = 0; j < 8; j++) a += q[c * 8 + j] * (float)kv[j];
    }
    lg[v] = a * 0.125f;
  }
#pragma unroll
  for (int v = 1; v < 13; v++)
    if (!((n >> (v - 1)) & 1)) lg[v] = -1e30f;

  float mx = lg[0];
#pragma unroll
  for (int v = 1; v < 13; v++) mx = fmaxf(mx, lg[v]);
  float w[13], s = 0.f;
#pragma unroll
  for (int v = 0; v < 13; v++) { w[v] = __expf(lg[v] - mx); s += w[v]; }
  const float inv = 1.0f / s;

  float o[64];
#pragma unroll
  for (int d = 0; d < 64; d++) o[d] = 0.f;
#pragma unroll
  for (int v = 0; v < 13; v++) {
    const int r = rows[v];
    const float wv = w[v];
#pragma unroll
    for (int c = 0; c < 8; c++) {
      const int cc = c ^ (r & 7);
      const bf16x8 vv = *(const bf16x8*)((const char*)Vl + r * 128 + cc * 16);
#pragma unroll
      for (int j = 0; j < 8; j++) o[c * 8 + j] += wv * (float)vv[j];
    }
  }

  bf16* Or = Ob + ((size_t)(bh >> 4) * L_SEQ + n) * 1024 + (size_t)(bh & 15) * 64;
#pragma unroll
  for (int c = 0; c < 8; c++) {
    bf16x8 ov;
#pragma unroll
    for (int j = 0; j < 8; j++) ov[j] = (bf16)(o[c * 8 + j] * inv);
    *(bf16x8*)(Or + c * 8) = ov;
  }
}

// ---------------------------------------------------------------------------
extern "C" void kernel_launch(void* const* d_in, const int* in_sizes, int n_in,
                              void* d_out, int out_size, void* d_ws, size_t ws_size,
                              hipStream_t stream) {
  const float* query = (const float*)d_in[0];
  const float* key   = (const float*)d_in[1];
  const float* value = (const float*)d_in[2];
  const float* Wq    = (const float*)d_in[3];
  const float* Wk    = (const float*)d_in[4];
  const float* Wv    = (const float*)d_in[5];
  const float* Wo    = (const float*)d_in[6];
  const float* bo    = (const float*)d_in[7];
  float* out = (float*)d_out;

  char* ws = (char*)d_ws;
  size_t off = 0;
  auto take = [&](size_t bytes) -> void* {
    void* p = ws + off;
    off += (bytes + 255) & ~(size_t)255;
    return p;
  };
  const size_t XB = (size_t)8192 * 1024 * 2;   // 16.78 MB
  const size_t WB = (size_t)1024 * 1024 * 2;   //  2.10 MB
  bf16* qx  = (bf16*)take(XB);
  bf16* kx  = (bf16*)take(XB);
  bf16* vx  = (bf16*)take(XB);
  bf16* wqx = (bf16*)take(WB);
  bf16* wkx = (bf16*)take(WB);
  bf16* wvx = (bf16*)take(WB);
  bf16* wox = (bf16*)take(WB);
  bf16* Qb  = (bf16*)take((size_t)32 * L_SEQ * 64 * 2);   // 16.78 MB
  bf16* fK  = (bf16*)take((size_t)32 * NFLAT * 64 * 2);   // 33.55 MB
  bf16* fV  = (bf16*)take((size_t)32 * NFLAT * 64 * 2);   // 33.55 MB
  bf16* Ob  = qx;  // alias: qx's last read is gemm8_qkv; Ob first written by attn
  (void)in_sizes; (void)n_in; (void)out_size; (void)ws_size;

  // 1. fp32 -> bf16
  cvt3_kernel<<<dim3(8192, 3), 256, 0, stream>>>(query, key, value, qx, kx, vx);
  cvt4_kernel<<<dim3(1024, 4), 256, 0, stream>>>(Wq, Wk, Wv, Wo, wqx, wkx, wvx, wox);

  // 2. Q/K/V projections (2-ring, 2 blocks/CU, XCD-chunked)
  gemm8_qkv_kernel<<<dim3(512, 3), 256, 0, stream>>>(qx, kx, vx, wqx, wkx, wvx, Qb, fK, fV);

  // 3. hierarchy
  tree_l16 <<<dim3(64, 32), 64, 0, stream>>>(fK, fV);
  tree_l712<<<32, 64, 0, stream>>>(fK, fV);

  // 4. sparse attention
  attn_kernel<<<dim3(64, 32), 64, 0, stream>>>(Qb, fK, fV, Ob);

  // 5. output projection
  gemm8_out_kernel<<<512, 256, 0, stream>>>(Ob, wox, bo, out);
}

// Round 8
// 160.938 us; speedup vs baseline: 1.2324x; 1.0269x over previous
//
#include <hip/hip_runtime.h>
#include <cstdint>
#include <cstddef>

// ---------------------------------------------------------------------------
// HierarchicalSparseAttention  B=2 L=4096 D=1024 H=16 DH=64
// cvt(f32->bf16, 1 launch) -> QKV GEMM (128x128 2-ring, XCD-chunked, K/V tree
// levels 1..6 fused in epilogue) -> tree_l712 -> sparse attn -> output GEMM
// ---------------------------------------------------------------------------

typedef __bf16 bf16;
typedef __bf16 bf16x8 __attribute__((ext_vector_type(8)));
typedef __bf16 bf16x4 __attribute__((ext_vector_type(4)));
typedef float  f32x4  __attribute__((ext_vector_type(4)));

#define L_SEQ  4096
#define NFLAT  8192   /* padded 2L-1 = 8191 */

__device__ __forceinline__ int off_l(int l) { return 8192 - (8192 >> l); }

// ---- async global->LDS, 16B per lane; lds base must be wave-uniform --------
__device__ __forceinline__ void glds16(const bf16* g, bf16* l) {
  __builtin_amdgcn_global_load_lds(
      (const __attribute__((address_space(1))) unsigned int*)g,
      (__attribute__((address_space(3))) unsigned int*)l, 16, 0, 0);
}

#define MEMFENCE asm volatile("" ::: "memory")
__device__ __forceinline__ void barrier_raw() {
  MEMFENCE; __builtin_amdgcn_s_barrier(); MEMFENCE;
}

// st_16x32 XOR swizzle (involution; permutes 16B chunks, preserves alignment)
__device__ __forceinline__ int swz(int b) { return b ^ (((b >> 9) & 1) << 5); }
// logical byte addr of (row, col) in a [R][64] bf16 tile stored as [16][32]
// subtiles (1024B each), 2 col-blocks per row-block
__device__ __forceinline__ int la(int row, int col) {
  return ((((row >> 4) << 1) + (col >> 5)) << 10) + ((row & 15) << 6) + ((col & 31) << 1);
}

// ---------------------------------------------------------------------------
// fp32 -> bf16 conversion: all 7 tensors in ONE launch. grid (8192, 4).
// y<3: q/k/v (2M float4 groups each). y==3: 4 weight tensors (256K groups ea).
// ---------------------------------------------------------------------------
__global__ __launch_bounds__(256) void cvtall_kernel(
    const float* __restrict__ q, const float* __restrict__ k, const float* __restrict__ v,
    const float* __restrict__ wq, const float* __restrict__ wk,
    const float* __restrict__ wv, const float* __restrict__ wo,
    bf16* __restrict__ qx, bf16* __restrict__ kx, bf16* __restrict__ vx,
    bf16* __restrict__ wqx, bf16* __restrict__ wkx, bf16* __restrict__ wvx,
    bf16* __restrict__ wox) {
  const int y = blockIdx.y;
  int i = blockIdx.x * 256 + threadIdx.x;
  const float* src; bf16* dst;
  if (y < 3) {
    src = (y == 0) ? q : (y == 1) ? k : v;
    dst = (y == 0) ? qx : (y == 1) ? kx : vx;
  } else {
    if (i >= 1048576) return;           // 4 x 262144 float4-groups
    const int w = i >> 18; i &= 262143;
    src = (w == 0) ? wq : (w == 1) ? wk : (w == 2) ? wv : wo;
    dst = (w == 0) ? wqx : (w == 1) ? wkx : (w == 2) ? wvx : wox;
  }
  const float4 t = ((const float4*)src)[i];
  bf16x4 o;
  o[0] = (bf16)t.x; o[1] = (bf16)t.y; o[2] = (bf16)t.z; o[3] = (bf16)t.w;
  *(bf16x4*)(dst + (size_t)i * 4) = o;
}

// ---------------------------------------------------------------------------
// GEMM: C(128x128) = A(128xK) * W(128xK)^T, K=1024, BK=64, bf16 MFMA.
// 256 threads = 4 waves (2M x 2N); wave output 64x64 = 4x4 frags 16x16x32.
// 2-buffer LDS ring (32KB each), depth-1 prefetch, swizzled LDS, one raw
// barrier per K-tile, setprio on MFMA. Staging: global_load_lds LINEAR dest
// + inverse-swizzled SOURCE (rule 21).
// ---------------------------------------------------------------------------
#define BUFB 32768   /* 16KB A + 16KB B */

__device__ __forceinline__ void stage_tile(const bf16* __restrict__ A,
                                           const bf16* __restrict__ W,
                                           int tm, int tn, int k0,
                                           char* buf, int tid, int wid) {
  bf16* Ad = (bf16*)buf;
  bf16* Bd = (bf16*)(buf + 16384);
#pragma unroll
  for (int i = 0; i < 4; i++) {
    const int d  = i * 4096 + tid * 16;
    const int lb = swz(d);
    const int row = ((lb >> 10) >> 1) * 16 + ((lb >> 6) & 15);
    const int col = ((lb >> 10) & 1) * 32 + ((lb & 63) >> 1);
    glds16(A + (size_t)(tm * 128 + row) * 1024 + k0 + col, Ad + ((i * 4096 + wid * 1024) >> 1));
    glds16(W + (size_t)(tn * 128 + row) * 1024 + k0 + col, Bd + ((i * 4096 + wid * 1024) >> 1));
  }
}

__device__ __forceinline__ void gemm8_core(const bf16* __restrict__ A,
                                           const bf16* __restrict__ W,
                                           int tm, int tn, char* lds,
                                           f32x4 (&acc)[4][4]) {
  const int tid  = threadIdx.x;
  const int wid  = tid >> 6, lane = tid & 63;
  const int wm   = wid >> 1, wn = wid & 1;
  const int laneR  = lane & 15;
  const int laneC8 = (lane >> 4) * 8;

  stage_tile(A, W, tm, tn, 0, lds, tid, wid);   // tile 0 -> buf 0

  for (int u = 0; u < 16; ++u) {
    // stage(u) was issued one full iteration ago; latency hidden under
    // iter u-1's compute + the sibling block on this CU.
    asm volatile("s_waitcnt vmcnt(0)" ::: "memory");
    barrier_raw();   // stage(u) visible to all; buf[(u+1)&1] fully consumed
    if (u + 1 < 16)
      stage_tile(A, W, tm, tn, (u + 1) << 6, lds + ((u + 1) & 1) * BUFB, tid, wid);

    const char* Ab = lds + (u & 1) * BUFB;
    const char* Bb = Ab + 16384;
    bf16x8 af[4][2], bfr[4][2];
#pragma unroll
    for (int f = 0; f < 4; f++)
#pragma unroll
      for (int ks = 0; ks < 2; ks++)
        af[f][ks] = *(const bf16x8*)(Ab + swz(la(wm * 64 + f * 16 + laneR, ks * 32 + laneC8)));
#pragma unroll
    for (int j = 0; j < 4; j++)
#pragma unroll
      for (int ks = 0; ks < 2; ks++)
        bfr[j][ks] = *(const bf16x8*)(Bb + swz(la(wn * 64 + j * 16 + laneR, ks * 32 + laneC8)));

    __builtin_amdgcn_s_setprio(1);
#pragma unroll
    for (int f = 0; f < 4; f++)
#pragma unroll
      for (int j = 0; j < 4; j++)
#pragma unroll
        for (int ks = 0; ks < 2; ks++)
          acc[f][j] = __builtin_amdgcn_mfma_f32_16x16x32_bf16(
              af[f][ks], bfr[j][ks], acc[f][j], 0, 0, 0);
    __builtin_amdgcn_s_setprio(0);
  }
}

// XCD-chunked bijective tile map (512 blocks/z, 8 XCDs, round-robin xcd=bid&7):
// XCD x owns tm in [8x, 8x+8) for all tn -> per-XCD working set L2-resident.
__device__ __forceinline__ void tile_map(int bid, int& tm, int& tn) {
  const int xcd = bid & 7, q = bid >> 3;
  tm = xcd * 8 + (q >> 3);
  tn = q & 7;
}

// QKV projections + fused K/V tree levels 1..6. grid = (512, 3).
// Tile = tokens [tm*128,+128) x heads {tn*2, tn*2+1} (complete) -> the block
// owns everything needed for levels 1..6 of its two 64-leaf groups.
__global__ __launch_bounds__(256, 2) void gemm8_qkv_kernel(
    const bf16* __restrict__ qx, const bf16* __restrict__ kx, const bf16* __restrict__ vx,
    const bf16* __restrict__ wq, const bf16* __restrict__ wk, const bf16* __restrict__ wv,
    bf16* __restrict__ Qb, bf16* __restrict__ fK, bf16* __restrict__ fV) {
  __shared__ __align__(16) char lds[2 * BUFB];
  const int z = blockIdx.y;
  const bf16* A = (z == 0) ? qx : (z == 1) ? kx : vx;
  const bf16* W = (z == 0) ? wq : (z == 1) ? wk : wv;
  bf16* D       = (z == 0) ? Qb : (z == 1) ? fK : fV;
  const int lstr = (z == 0) ? L_SEQ : NFLAT;
  int tm, tn; tile_map(blockIdx.x, tm, tn);
  f32x4 acc[4][4] = {};
  gemm8_core(A, W, tm, tn, lds, acc);

  const int lane = threadIdx.x & 63, wid = threadIdx.x >> 6;
  const int rl0 = (wid >> 1) * 64 + (lane >> 4) * 4;   // local row
  const int cl0 = (wid & 1) * 64 + (lane & 15);        // local col
  // ---- C -> global (Q rows / K,V level-0) ----
#pragma unroll
  for (int i = 0; i < 4; i++)
#pragma unroll
    for (int j = 0; j < 4; j++)
#pragma unroll
      for (int r = 0; r < 4; r++) {
        const int m = tm * 128 + rl0 + i * 16 + r;
        const int n = tn * 128 + cl0 + j * 16;
        const int b = m >> 12, l = m & 4095;
        const int h = n >> 6,  dh = n & 63;
        D[((size_t)(b * 16 + h) * lstr + l) * 64 + dh] = (bf16)acc[i][j][r];
      }

  // ---- fused tree levels 1..6 (K and V blocks only) ----
  if (z != 0) {
    bf16* Ct = (bf16*)lds;                 // [128][132] bf16 = 33792B
    barrier_raw();                         // all waves done reading ring bufs
#pragma unroll
    for (int i = 0; i < 4; i++)
#pragma unroll
      for (int j = 0; j < 4; j++)
#pragma unroll
        for (int r = 0; r < 4; r++)
          Ct[(rl0 + i * 16 + r) * 132 + (cl0 + j * 16)] = (bf16)acc[i][j][r];
    barrier_raw();

    const int g2 = threadIdx.x >> 7;       // 64-leaf group within tile
    const int c  = threadIdx.x & 127;      // local col
    const int h  = tn * 2 + (c >> 6), dh = c & 63;
    const int b  = (tm * 128) >> 12;
    const int lbase = ((tm * 128) & 4095) + g2 * 64;
    const size_t fb = (size_t)(b * 16 + h) * NFLAT * 64 + dh;
    float pk[7];
#pragma unroll
    for (int i = 0; i < 64; i++) {
      float ck = (float)Ct[(g2 * 64 + i) * 132 + c];
#pragma unroll
      for (int l = 1; l <= 6; l++) {
        if (((i + 1) & ((1 << l) - 1)) != 0) { pk[l] = ck; break; }
        ck += pk[l];
        const int j = (lbase + i) >> l;
        D[fb + (size_t)(off_l(l) + j) * 64] =
            (bf16)(z == 1 ? ck * (1.0f / (1 << l)) : ck);
      }
    }
  }
}

// Output projection + bias, f32 out (8192 x 1024). grid = 512.
__global__ __launch_bounds__(256, 2) void gemm8_out_kernel(
    const bf16* __restrict__ Ob, const bf16* __restrict__ wo,
    const float* __restrict__ bo, float* __restrict__ out) {
  __shared__ __align__(16) char lds[2 * BUFB];
  int tm, tn; tile_map(blockIdx.x, tm, tn);
  f32x4 acc[4][4] = {};
  gemm8_core(Ob, wo, tm, tn, lds, acc);
  const int lane = threadIdx.x & 63, wid = threadIdx.x >> 6;
  const int m0 = tm * 128 + (wid >> 1) * 64 + (lane >> 4) * 4;
  const int n0 = tn * 128 + (wid & 1) * 64 + (lane & 15);
#pragma unroll
  for (int i = 0; i < 4; i++)
#pragma unroll
    for (int j = 0; j < 4; j++)
#pragma unroll
      for (int r = 0; r < 4; r++) {
        const int m = m0 + i * 16 + r;
        const int n = n0 + j * 16;
        out[(size_t)m * 1024 + n] = acc[i][j][r] + bo[n];
      }
}

// ---------------------------------------------------------------------------
// Tree levels 7..12 from level 6. Block = 1 wave per bh, lane = column d.
// grid = 32
// ---------------------------------------------------------------------------
__global__ __launch_bounds__(64) void tree_l712(bf16* __restrict__ fK, bf16* __restrict__ fV) {
  __shared__ float Ks[64 * 64];
  __shared__ float Vs[64 * 64];
  const int bh = blockIdx.x, d = threadIdx.x;
  const size_t fb = (size_t)bh * NFLAT * 64;
#pragma unroll 8
  for (int i = 0; i < 64; i++) {
    Ks[i * 64 + d] = (float)fK[fb + (size_t)(8064 + i) * 64 + d];  // off_l(6)=8064
    Vs[i * 64 + d] = (float)fV[fb + (size_t)(8064 + i) * 64 + d];
  }
#pragma unroll
  for (int l = 7; l <= 12; l++) {
    const int cnt = 4096 >> l;   // 32,16,8,4,2,1
    for (int j = 0; j < cnt; j++) {
      const float k = (Ks[(2 * j) * 64 + d] + Ks[(2 * j + 1) * 64 + d]) * 0.5f;
      const float v =  Vs[(2 * j) * 64 + d] + Vs[(2 * j + 1) * 64 + d];
      Ks[j * 64 + d] = k;
      Vs[j * 64 + d] = v;
      fK[fb + (size_t)(off_l(l) + j) * 64 + d] = (bf16)k;
      fV[fb + (size_t)(off_l(l) + j) * 64 + d] = (bf16)v;
    }
  }
}

// ---------------------------------------------------------------------------
// Sparse attention: per token 13 candidates (self + levels 0..11).
//   neighbor flat idx at level l = OFF(l) + ((n>>l)^1); valid iff (n>>l)&1.
// Block = 1 wave = 64 consecutive tokens of one (b,h); 132 K/V rows in LDS
// (XOR-swizzled chunks). grid = (64, 32)
// ---------------------------------------------------------------------------
__global__ __launch_bounds__(64) void attn_kernel(
    const bf16* __restrict__ Qb, const bf16* __restrict__ fK,
    const bf16* __restrict__ fV, bf16* __restrict__ Ob) {
  __shared__ __align__(16) unsigned short Kl[132 * 64];
  __shared__ __align__(16) unsigned short Vl[132 * 64];
  const int t0  = blockIdx.x * 64;
  const int bh  = blockIdx.y;
  const int tid = threadIdx.x;
  const size_t fb = (size_t)bh * NFLAT * 64;

  for (int u = tid; u < 132 * 8; u += 64) {
    const int r = u >> 3, c = u & 7;
    int flat;
    if      (r < 64)  flat = t0 + r;
    else if (r < 96)  flat = 4096 + (t0 >> 1) + (r - 64);
    else if (r < 112) flat = 6144 + (t0 >> 2) + (r - 96);
    else if (r < 120) flat = 7168 + (t0 >> 3) + (r - 112);
    else if (r < 124) flat = 7680 + (t0 >> 4) + (r - 120);
    else if (r < 126) flat = 7936 + (t0 >> 5) + (r - 124);
    else { const int l = r - 120; flat = (8192 - (8192 >> l) + (t0 >> l)) ^ 1; }
    const int cc = c ^ (r & 7);
    const uint4 kk = *(const uint4*)((const char*)(fK + fb + (size_t)flat * 64) + c * 16);
    const uint4 vv = *(const uint4*)((const char*)(fV + fb + (size_t)flat * 64) + c * 16);
    *(uint4*)((char*)Kl + r * 128 + cc * 16) = kk;
    *(uint4*)((char*)Vl + r * 128 + cc * 16) = vv;
  }
  __syncthreads();

  const int n = t0 + tid;
  int rows[13];
  rows[0] = tid;
#pragma unroll
  for (int l = 0; l < 12; l++) {
    int r;
    if (l == 0)      r = tid ^ 1;
    else if (l <= 5) r = (128 - (128 >> l)) + (((n >> l) ^ 1) - (t0 >> l));
    else             r = 126 + (l - 6);
    rows[l + 1] = r;
  }

  float q[64];
  const bf16* Qr = Qb + ((size_t)bh * L_SEQ + n) * 64;
#pragma unroll
  for (int c = 0; c < 8; c++) {
    bf16x8 v = *(const bf16x8*)(Qr + c * 8);
#pragma unroll
    for (int j = 0; j < 8; j++) q[c * 8 + j] = (float)v[j];
  }

  float lg[13];
#pragma unroll
  for (int v = 0; v < 13; v++) {
    const int r = rows[v];
    float a = 0.f;
#pragma unroll
    for (int c = 0; c < 8; c++) {
      const int cc = c ^ (r & 7);
      const bf16x8 kv = *(const bf16x8*)((const char*)Kl + r * 128 + cc * 16);
#pragma unroll
      for (int j = 0; j < 8; j++) a += q[c * 8 + j] * (float)kv[j];
    }
    lg[v] = a * 0.125f;
  }
#pragma unroll
  for (int v = 1; v < 13; v++)
    if (!((n >> (v - 1)) & 1)) lg[v] = -1e30f;

  float mx = lg[0];
#pragma unroll
  for (int v = 1; v < 13; v++) mx = fmaxf(mx, lg[v]);
  float w[13], s = 0.f;
#pragma unroll
  for (int v = 0; v < 13; v++) { w[v] = __expf(lg[v] - mx); s += w[v]; }
  const float inv = 1.0f / s;

  float o[64];
#pragma unroll
  for (int d = 0; d < 64; d++) o[d] = 0.f;
#pragma unroll
  for (int v = 0; v < 13; v++) {
    const int r = rows[v];
    const float wv = w[v];
#pragma unroll
    for (int c = 0; c < 8; c++) {
      const int cc = c ^ (r & 7);
      const bf16x8 vv = *(const bf16x8*)((const char*)Vl + r * 128 + cc * 16);
#pragma unroll
      for (int j = 0; j < 8; j++) o[c * 8 + j] += wv * (float)vv[j];
    }
  }

  bf16* Or = Ob + ((size_t)(bh >> 4) * L_SEQ + n) * 1024 + (size_t)(bh & 15) * 64;
#pragma unroll
  for (int c = 0; c < 8; c++) {
    bf16x8 ov;
#pragma unroll
    for (int j = 0; j < 8; j++) ov[j] = (bf16)(o[c * 8 + j] * inv);
    *(bf16x8*)(Or + c * 8) = ov;
  }
}

// ---------------------------------------------------------------------------
extern "C" void kernel_launch(void* const* d_in, const int* in_sizes, int n_in,
                              void* d_out, int out_size, void* d_ws, size_t ws_size,
                              hipStream_t stream) {
  const float* query = (const float*)d_in[0];
  const float* key   = (const float*)d_in[1];
  const float* value = (const float*)d_in[2];
  const float* Wq    = (const float*)d_in[3];
  const float* Wk    = (const float*)d_in[4];
  const float* Wv    = (const float*)d_in[5];
  const float* Wo    = (const float*)d_in[6];
  const float* bo    = (const float*)d_in[7];
  float* out = (float*)d_out;

  char* ws = (char*)d_ws;
  size_t off = 0;
  auto take = [&](size_t bytes) -> void* {
    void* p = ws + off;
    off += (bytes + 255) & ~(size_t)255;
    return p;
  };
  const size_t XB = (size_t)8192 * 1024 * 2;   // 16.78 MB
  const size_t WB = (size_t)1024 * 1024 * 2;   //  2.10 MB
  bf16* qx  = (bf16*)take(XB);
  bf16* kx  = (bf16*)take(XB);
  bf16* vx  = (bf16*)take(XB);
  bf16* wqx = (bf16*)take(WB);
  bf16* wkx = (bf16*)take(WB);
  bf16* wvx = (bf16*)take(WB);
  bf16* wox = (bf16*)take(WB);
  bf16* Qb  = (bf16*)take((size_t)32 * L_SEQ * 64 * 2);   // 16.78 MB
  bf16* fK  = (bf16*)take((size_t)32 * NFLAT * 64 * 2);   // 33.55 MB
  bf16* fV  = (bf16*)take((size_t)32 * NFLAT * 64 * 2);   // 33.55 MB
  bf16* Ob  = qx;  // alias: qx's last read is gemm8_qkv; Ob first written by attn
  (void)in_sizes; (void)n_in; (void)out_size; (void)ws_size;

  // 1. fp32 -> bf16 (single launch)
  cvtall_kernel<<<dim3(8192, 4), 256, 0, stream>>>(
      query, key, value, Wq, Wk, Wv, Wo, qx, kx, vx, wqx, wkx, wvx, wox);

  // 2. Q/K/V projections + tree levels 1..6 (fused epilogue)
  gemm8_qkv_kernel<<<dim3(512, 3), 256, 0, stream>>>(qx, kx, vx, wqx, wkx, wvx, Qb, fK, fV);

  // 3. tree levels 7..12
  tree_l712<<<32, 64, 0, stream>>>(fK, fV);

  // 4. sparse attention
  attn_kernel<<<dim3(64, 32), 64, 0, stream>>>(Qb, fK, fV, Ob);

  // 5. output projection
  gemm8_out_kernel<<<512, 256, 0, stream>>>(Ob, wox, bo, out);
}

// Round 9
// 159.532 us; speedup vs baseline: 1.2433x; 1.0088x over previous
//
#include <hip/hip_runtime.h>
#include <cstdint>
#include <cstddef>

// ---------------------------------------------------------------------------
// HierarchicalSparseAttention  B=2 L=4096 D=1024 H=16 DH=64
// cvt(f32->bf16, grid-stride 1 launch) -> QKV GEMM (128x128 2-ring,
// XCD-chunked, K/V tree levels 1..6 fused) -> tree_l712 -> sparse attn
// (68-row LDS staging, lvl-0 direct) -> output GEMM (+bias, f32)
// ---------------------------------------------------------------------------

typedef __bf16 bf16;
typedef __bf16 bf16x8 __attribute__((ext_vector_type(8)));
typedef __bf16 bf16x4 __attribute__((ext_vector_type(4)));
typedef float  f32x4  __attribute__((ext_vector_type(4)));

#define L_SEQ  4096
#define NFLAT  8192   /* padded 2L-1 = 8191 */

__device__ __forceinline__ int off_l(int l) { return 8192 - (8192 >> l); }

// ---- async global->LDS, 16B per lane; lds base must be wave-uniform --------
__device__ __forceinline__ void glds16(const bf16* g, bf16* l) {
  __builtin_amdgcn_global_load_lds(
      (const __attribute__((address_space(1))) unsigned int*)g,
      (__attribute__((address_space(3))) unsigned int*)l, 16, 0, 0);
}

#define MEMFENCE asm volatile("" ::: "memory")
__device__ __forceinline__ void barrier_raw() {
  MEMFENCE; __builtin_amdgcn_s_barrier(); MEMFENCE;
}

// st_16x32 XOR swizzle (involution; permutes 16B chunks, preserves alignment)
__device__ __forceinline__ int swz(int b) { return b ^ (((b >> 9) & 1) << 5); }
// logical byte addr of (row, col) in a [R][64] bf16 tile stored as [16][32]
// subtiles (1024B each), 2 col-blocks per row-block
__device__ __forceinline__ int la(int row, int col) {
  return ((((row >> 4) << 1) + (col >> 5)) << 10) + ((row & 15) << 6) + ((col & 31) << 1);
}

// ---------------------------------------------------------------------------
// fp32 -> bf16: all 7 tensors, grid-stride, 32B/lane. grid = 2048 x 256.
// 8-elem groups: 3 x 1048576 (q,k,v) + 4 x 131072 (weights) = 3670016 total.
// ---------------------------------------------------------------------------
__global__ __launch_bounds__(256) void cvtall_kernel(
    const float* __restrict__ q, const float* __restrict__ k, const float* __restrict__ v,
    const float* __restrict__ wq, const float* __restrict__ wk,
    const float* __restrict__ wv, const float* __restrict__ wo,
    bf16* __restrict__ qx, bf16* __restrict__ kx, bf16* __restrict__ vx,
    bf16* __restrict__ wqx, bf16* __restrict__ wkx, bf16* __restrict__ wvx,
    bf16* __restrict__ wox) {
  for (int i = blockIdx.x * 256 + threadIdx.x; i < 3670016; i += 524288) {
    int g = i;
    const float* s; bf16* d;
    if (g < 3145728) {
      const int t = g >> 20; g &= 1048575;
      s = (t == 0) ? q : (t == 1) ? k : v;
      d = (t == 0) ? qx : (t == 1) ? kx : vx;
    } else {
      int gg = g - 3145728;
      const int t = gg >> 17; g = gg & 131071;
      s = (t == 0) ? wq : (t == 1) ? wk : (t == 2) ? wv : wo;
      d = (t == 0) ? wqx : (t == 1) ? wkx : (t == 2) ? wvx : wox;
    }
    const float4 v0 = ((const float4*)s)[(size_t)g * 2];
    const float4 v1 = ((const float4*)s)[(size_t)g * 2 + 1];
    bf16x8 o;
    o[0] = (bf16)v0.x; o[1] = (bf16)v0.y; o[2] = (bf16)v0.z; o[3] = (bf16)v0.w;
    o[4] = (bf16)v1.x; o[5] = (bf16)v1.y; o[6] = (bf16)v1.z; o[7] = (bf16)v1.w;
    *(bf16x8*)(d + (size_t)g * 8) = o;
  }
}

// ---------------------------------------------------------------------------
// GEMM: C(128x128) = A(128xK) * W(128xK)^T, K=1024, BK=64, bf16 MFMA.
// 256 threads = 4 waves (2M x 2N); wave output 64x64 = 4x4 frags 16x16x32.
// 2-buffer LDS ring (32KB each), depth-1 prefetch, swizzled LDS, one raw
// barrier per K-tile, setprio on MFMA. Staging: global_load_lds LINEAR dest
// + inverse-swizzled SOURCE (rule 21).
// ---------------------------------------------------------------------------
#define BUFB 32768   /* 16KB A + 16KB B */

__device__ __forceinline__ void stage_tile(const bf16* __restrict__ A,
                                           const bf16* __restrict__ W,
                                           int tm, int tn, int k0,
                                           char* buf, int tid, int wid) {
  bf16* Ad = (bf16*)buf;
  bf16* Bd = (bf16*)(buf + 16384);
#pragma unroll
  for (int i = 0; i < 4; i++) {
    const int d  = i * 4096 + tid * 16;
    const int lb = swz(d);
    const int row = ((lb >> 10) >> 1) * 16 + ((lb >> 6) & 15);
    const int col = ((lb >> 10) & 1) * 32 + ((lb & 63) >> 1);
    glds16(A + (size_t)(tm * 128 + row) * 1024 + k0 + col, Ad + ((i * 4096 + wid * 1024) >> 1));
    glds16(W + (size_t)(tn * 128 + row) * 1024 + k0 + col, Bd + ((i * 4096 + wid * 1024) >> 1));
  }
}

__device__ __forceinline__ void gemm8_core(const bf16* __restrict__ A,
                                           const bf16* __restrict__ W,
                                           int tm, int tn, char* lds,
                                           f32x4 (&acc)[4][4]) {
  const int tid  = threadIdx.x;
  const int wid  = tid >> 6, lane = tid & 63;
  const int wm   = wid >> 1, wn = wid & 1;
  const int laneR  = lane & 15;
  const int laneC8 = (lane >> 4) * 8;

  stage_tile(A, W, tm, tn, 0, lds, tid, wid);   // tile 0 -> buf 0

  for (int u = 0; u < 16; ++u) {
    asm volatile("s_waitcnt vmcnt(0)" ::: "memory");
    barrier_raw();   // stage(u) visible to all; buf[(u+1)&1] fully consumed
    if (u + 1 < 16)
      stage_tile(A, W, tm, tn, (u + 1) << 6, lds + ((u + 1) & 1) * BUFB, tid, wid);

    const char* Ab = lds + (u & 1) * BUFB;
    const char* Bb = Ab + 16384;
    bf16x8 af[4][2], bfr[4][2];
#pragma unroll
    for (int f = 0; f < 4; f++)
#pragma unroll
      for (int ks = 0; ks < 2; ks++)
        af[f][ks] = *(const bf16x8*)(Ab + swz(la(wm * 64 + f * 16 + laneR, ks * 32 + laneC8)));
#pragma unroll
    for (int j = 0; j < 4; j++)
#pragma unroll
      for (int ks = 0; ks < 2; ks++)
        bfr[j][ks] = *(const bf16x8*)(Bb + swz(la(wn * 64 + j * 16 + laneR, ks * 32 + laneC8)));

    __builtin_amdgcn_s_setprio(1);
#pragma unroll
    for (int f = 0; f < 4; f++)
#pragma unroll
      for (int j = 0; j < 4; j++)
#pragma unroll
        for (int ks = 0; ks < 2; ks++)
          acc[f][j] = __builtin_amdgcn_mfma_f32_16x16x32_bf16(
              af[f][ks], bfr[j][ks], acc[f][j], 0, 0, 0);
    __builtin_amdgcn_s_setprio(0);
  }
}

// XCD-chunked bijective tile map (512 blocks/z, 8 XCDs, round-robin xcd=bid&7):
// XCD x owns tm in [8x, 8x+8) for all tn -> per-XCD working set L2-resident.
__device__ __forceinline__ void tile_map(int bid, int& tm, int& tn) {
  const int xcd = bid & 7, q = bid >> 3;
  tm = xcd * 8 + (q >> 3);
  tn = q & 7;
}

// QKV projections + fused K/V tree levels 1..6. grid = (512, 3).
__global__ __launch_bounds__(256, 2) void gemm8_qkv_kernel(
    const bf16* __restrict__ qx, const bf16* __restrict__ kx, const bf16* __restrict__ vx,
    const bf16* __restrict__ wq, const bf16* __restrict__ wk, const bf16* __restrict__ wv,
    bf16* __restrict__ Qb, bf16* __restrict__ fK, bf16* __restrict__ fV) {
  __shared__ __align__(16) char lds[2 * BUFB];
  const int z = blockIdx.y;
  const bf16* A = (z == 0) ? qx : (z == 1) ? kx : vx;
  const bf16* W = (z == 0) ? wq : (z == 1) ? wk : wv;
  bf16* D       = (z == 0) ? Qb : (z == 1) ? fK : fV;
  const int lstr = (z == 0) ? L_SEQ : NFLAT;
  int tm, tn; tile_map(blockIdx.x, tm, tn);
  f32x4 acc[4][4] = {};
  gemm8_core(A, W, tm, tn, lds, acc);

  const int lane = threadIdx.x & 63, wid = threadIdx.x >> 6;
  const int rl0 = (wid >> 1) * 64 + (lane >> 4) * 4;   // local row
  const int cl0 = (wid & 1) * 64 + (lane & 15);        // local col
#pragma unroll
  for (int i = 0; i < 4; i++)
#pragma unroll
    for (int j = 0; j < 4; j++)
#pragma unroll
      for (int r = 0; r < 4; r++) {
        const int m = tm * 128 + rl0 + i * 16 + r;
        const int n = tn * 128 + cl0 + j * 16;
        const int b = m >> 12, l = m & 4095;
        const int h = n >> 6,  dh = n & 63;
        D[((size_t)(b * 16 + h) * lstr + l) * 64 + dh] = (bf16)acc[i][j][r];
      }

  // ---- fused tree levels 1..6 (K and V blocks only) ----
  if (z != 0) {
    bf16* Ct = (bf16*)lds;                 // [128][132] bf16 = 33792B
    barrier_raw();                         // all waves done reading ring bufs
#pragma unroll
    for (int i = 0; i < 4; i++)
#pragma unroll
      for (int j = 0; j < 4; j++)
#pragma unroll
        for (int r = 0; r < 4; r++)
          Ct[(rl0 + i * 16 + r) * 132 + (cl0 + j * 16)] = (bf16)acc[i][j][r];
    barrier_raw();

    const int g2 = threadIdx.x >> 7;       // 64-leaf group within tile
    const int c  = threadIdx.x & 127;      // local col
    const int h  = tn * 2 + (c >> 6), dh = c & 63;
    const int b  = (tm * 128) >> 12;
    const int lbase = ((tm * 128) & 4095) + g2 * 64;
    const size_t fb = (size_t)(b * 16 + h) * NFLAT * 64 + dh;
    float pk[7];
#pragma unroll
    for (int i = 0; i < 64; i++) {
      float ck = (float)Ct[(g2 * 64 + i) * 132 + c];
#pragma unroll
      for (int l = 1; l <= 6; l++) {
        if (((i + 1) & ((1 << l) - 1)) != 0) { pk[l] = ck; break; }
        ck += pk[l];
        const int j = (lbase + i) >> l;
        D[fb + (size_t)(off_l(l) + j) * 64] =
            (bf16)(z == 1 ? ck * (1.0f / (1 << l)) : ck);
      }
    }
  }
}

// Output projection + bias, f32 out (8192 x 1024). grid = 512.
__global__ __launch_bounds__(256, 2) void gemm8_out_kernel(
    const bf16* __restrict__ Ob, const bf16* __restrict__ wo,
    const float* __restrict__ bo, float* __restrict__ out) {
  __shared__ __align__(16) char lds[2 * BUFB];
  int tm, tn; tile_map(blockIdx.x, tm, tn);
  f32x4 acc[4][4] = {};
  gemm8_core(Ob, wo, tm, tn, lds, acc);
  const int lane = threadIdx.x & 63, wid = threadIdx.x >> 6;
  const int m0 = tm * 128 + (wid >> 1) * 64 + (lane >> 4) * 4;
  const int n0 = tn * 128 + (wid & 1) * 64 + (lane & 15);
#pragma unroll
  for (int i = 0; i < 4; i++)
#pragma unroll
    for (int j = 0; j < 4; j++)
#pragma unroll
      for (int r = 0; r < 4; r++) {
        const int m = m0 + i * 16 + r;
        const int n = n0 + j * 16;
        out[(size_t)m * 1024 + n] = acc[i][j][r] + bo[n];
      }
}

// ---------------------------------------------------------------------------
// Tree levels 7..12 from level 6. Block = 1 wave per bh, lane = column d.
// grid = 32
// ---------------------------------------------------------------------------
__global__ __launch_bounds__(64) void tree_l712(bf16* __restrict__ fK, bf16* __restrict__ fV) {
  __shared__ float Ks[64 * 64];
  __shared__ float Vs[64 * 64];
  const int bh = blockIdx.x, d = threadIdx.x;
  const size_t fb = (size_t)bh * NFLAT * 64;
#pragma unroll 8
  for (int i = 0; i < 64; i++) {
    Ks[i * 64 + d] = (float)fK[fb + (size_t)(8064 + i) * 64 + d];  // off_l(6)=8064
    Vs[i * 64 + d] = (float)fV[fb + (size_t)(8064 + i) * 64 + d];
  }
#pragma unroll
  for (int l = 7; l <= 12; l++) {
    const int cnt = 4096 >> l;   // 32,16,8,4,2,1
    for (int j = 0; j < cnt; j++) {
      const float k = (Ks[(2 * j) * 64 + d] + Ks[(2 * j + 1) * 64 + d]) * 0.5f;
      const float v =  Vs[(2 * j) * 64 + d] + Vs[(2 * j + 1) * 64 + d];
      Ks[j * 64 + d] = k;
      Vs[j * 64 + d] = v;
      fK[fb + (size_t)(off_l(l) + j) * 64 + d] = (bf16)k;
      fV[fb + (size_t)(off_l(l) + j) * 64 + d] = (bf16)v;
    }
  }
}

// ---------------------------------------------------------------------------
// Sparse attention: per token 13 candidates (self + levels 0..11).
//   neighbor flat idx at level l = OFF(l) + ((n>>l)^1); valid iff (n>>l)&1.
// Block = 1 wave = 64 consecutive tokens of one (b,h). LDS stages only the
// 68 SHARED tree rows (levels 1..11, 17KB -> ~9 blocks/CU); per-lane level-0
// rows (self + tid^1) read direct from global (L2-resident). grid = (64, 32)
// ---------------------------------------------------------------------------
__global__ __launch_bounds__(64) void attn_kernel(
    const bf16* __restrict__ Qb, const bf16* __restrict__ fK,
    const bf16* __restrict__ fV, bf16* __restrict__ Ob) {
  __shared__ __align__(16) unsigned short Kl[68 * 64];
  __shared__ __align__(16) unsigned short Vl[68 * 64];
  const int t0  = blockIdx.x * 64;
  const int bh  = blockIdx.y;
  const int tid = threadIdx.x;
  const size_t fb = (size_t)bh * NFLAT * 64;

  // --- stage 68 tree rows (levels 1..11) of K and V, XOR-swizzled chunks ---
  for (int u = tid; u < 68 * 8; u += 64) {
    const int r = u >> 3, c = u & 7;
    int flat;
    if      (r < 32) flat = 4096 + (t0 >> 1) + r;         // level 1
    else if (r < 48) flat = 6144 + (t0 >> 2) + (r - 32);  // level 2
    else if (r < 56) flat = 7168 + (t0 >> 3) + (r - 48);  // level 3
    else if (r < 60) flat = 7680 + (t0 >> 4) + (r - 56);  // level 4
    else if (r < 62) flat = 7936 + (t0 >> 5) + (r - 60);  // level 5
    else { const int l = r - 56; flat = (8192 - (8192 >> l) + (t0 >> l)) ^ 1; } // lvl 6..11
    const int cc = c ^ (r & 7);
    const uint4 kk = *(const uint4*)((const char*)(fK + fb + (size_t)flat * 64) + c * 16);
    const uint4 vv = *(const uint4*)((const char*)(fV + fb + (size_t)flat * 64) + c * 16);
    *(uint4*)((char*)Kl + r * 128 + cc * 16) = kk;
    *(uint4*)((char*)Vl + r * 128 + cc * 16) = vv;
  }
  __syncthreads();

  const int n = t0 + tid;
  // staged-row index for levels 1..11 (candidate v = l+1)
  int rows[13];   // rows[0],rows[1] unused (direct global path)
#pragma unroll
  for (int l = 1; l < 12; l++) {
    int r;
    if (l <= 5) r = (64 - (128 >> l)) + (((n >> l) ^ 1) - (t0 >> l));
    else        r = 62 + (l - 6);
    rows[l + 1] = r;
  }

  // Q row -> 64 f32 regs
  float q[64];
  const bf16* Qr = Qb + ((size_t)bh * L_SEQ + n) * 64;
#pragma unroll
  for (int c = 0; c < 8; c++) {
    bf16x8 v = *(const bf16x8*)(Qr + c * 8);
#pragma unroll
    for (int j = 0; j < 8; j++) q[c * 8 + j] = (float)v[j];
  }

  // logits: self + lvl-0 neighbor from global; levels 1..11 from LDS
  float lg[13];
  {
    const bf16* Ks0 = fK + fb + (size_t)(t0 + tid) * 64;
    const bf16* Kn0 = fK + fb + (size_t)(t0 + (tid ^ 1)) * 64;
    float a0 = 0.f, a1 = 0.f;
#pragma unroll
    for (int c = 0; c < 8; c++) {
      const bf16x8 s = *(const bf16x8*)(Ks0 + c * 8);
      const bf16x8 t = *(const bf16x8*)(Kn0 + c * 8);
#pragma unroll
      for (int j = 0; j < 8; j++) { a0 += q[c * 8 + j] * (float)s[j]; a1 += q[c * 8 + j] * (float)t[j]; }
    }
    lg[0] = a0 * 0.125f; lg[1] = a1 * 0.125f;
  }
#pragma unroll
  for (int v = 2; v < 13; v++) {
    const int r = rows[v];
    float a = 0.f;
#pragma unroll
    for (int c = 0; c < 8; c++) {
      const int cc = c ^ (r & 7);
      const bf16x8 kv = *(const bf16x8*)((const char*)Kl + r * 128 + cc * 16);
#pragma unroll
      for (int j = 0; j < 8; j++) a += q[c * 8 + j] * (float)kv[j];
    }
    lg[v] = a * 0.125f;
  }
#pragma unroll
  for (int v = 1; v < 13; v++)
    if (!((n >> (v - 1)) & 1)) lg[v] = -1e30f;

  // softmax over 13
  float mx = lg[0];
#pragma unroll
  for (int v = 1; v < 13; v++) mx = fmaxf(mx, lg[v]);
  float w[13], s = 0.f;
#pragma unroll
  for (int v = 0; v < 13; v++) { w[v] = __expf(lg[v] - mx); s += w[v]; }
  const float inv = 1.0f / s;

  // weighted V sum: v=0,1 from global; v>=2 from LDS
  float o[64];
#pragma unroll
  for (int d = 0; d < 64; d++) o[d] = 0.f;
  {
    const bf16* Vs0 = fV + fb + (size_t)(t0 + tid) * 64;
    const bf16* Vn0 = fV + fb + (size_t)(t0 + (tid ^ 1)) * 64;
    const float w0 = w[0], w1 = w[1];
#pragma unroll
    for (int c = 0; c < 8; c++) {
      const bf16x8 s0 = *(const bf16x8*)(Vs0 + c * 8);
      const bf16x8 t1 = *(const bf16x8*)(Vn0 + c * 8);
#pragma unroll
      for (int j = 0; j < 8; j++) o[c * 8 + j] += w0 * (float)s0[j] + w1 * (float)t1[j];
    }
  }
#pragma unroll
  for (int v = 2; v < 13; v++) {
    const int r = rows[v];
    const float wv = w[v];
#pragma unroll
    for (int c = 0; c < 8; c++) {
      const int cc = c ^ (r & 7);
      const bf16x8 vv = *(const bf16x8*)((const char*)Vl + r * 128 + cc * 16);
#pragma unroll
      for (int j = 0; j < 8; j++) o[c * 8 + j] += wv * (float)vv[j];
    }
  }

  bf16* Or = Ob + ((size_t)(bh >> 4) * L_SEQ + n) * 1024 + (size_t)(bh & 15) * 64;
#pragma unroll
  for (int c = 0; c < 8; c++) {
    bf16x8 ov;
#pragma unroll
    for (int j = 0; j < 8; j++) ov[j] = (bf16)(o[c * 8 + j] * inv);
    *(bf16x8*)(Or + c * 8) = ov;
  }
}

// ---------------------------------------------------------------------------
extern "C" void kernel_launch(void* const* d_in, const int* in_sizes, int n_in,
                              void* d_out, int out_size, void* d_ws, size_t ws_size,
                              hipStream_t stream) {
  const float* query = (const float*)d_in[0];
  const float* key   = (const float*)d_in[1];
  const float* value = (const float*)d_in[2];
  const float* Wq    = (const float*)d_in[3];
  const float* Wk    = (const float*)d_in[4];
  const float* Wv    = (const float*)d_in[5];
  const float* Wo    = (const float*)d_in[6];
  const float* bo    = (const float*)d_in[7];
  float* out = (float*)d_out;

  char* ws = (char*)d_ws;
  size_t off = 0;
  auto take = [&](size_t bytes) -> void* {
    void* p = ws + off;
    off += (bytes + 255) & ~(size_t)255;
    return p;
  };
  const size_t XB = (size_t)8192 * 1024 * 2;   // 16.78 MB
  const size_t WB = (size_t)1024 * 1024 * 2;   //  2.10 MB
  bf16* qx  = (bf16*)take(XB);
  bf16* kx  = (bf16*)take(XB);
  bf16* vx  = (bf16*)take(XB);
  bf16* wqx = (bf16*)take(WB);
  bf16* wkx = (bf16*)take(WB);
  bf16* wvx = (bf16*)take(WB);
  bf16* wox = (bf16*)take(WB);
  bf16* Qb  = (bf16*)take((size_t)32 * L_SEQ * 64 * 2);   // 16.78 MB
  bf16* fK  = (bf16*)take((size_t)32 * NFLAT * 64 * 2);   // 33.55 MB
  bf16* fV  = (bf16*)take((size_t)32 * NFLAT * 64 * 2);   // 33.55 MB
  bf16* Ob  = qx;  // alias: qx's last read is gemm8_qkv; Ob first written by attn
  (void)in_sizes; (void)n_in; (void)out_size; (void)ws_size;

  // 1. fp32 -> bf16 (grid-stride, single launch)
  cvtall_kernel<<<2048, 256, 0, stream>>>(
      query, key, value, Wq, Wk, Wv, Wo, qx, kx, vx, wqx, wkx, wvx, wox);

  // 2. Q/K/V projections + tree levels 1..6 (fused epilogue)
  gemm8_qkv_kernel<<<dim3(512, 3), 256, 0, stream>>>(qx, kx, vx, wqx, wkx, wvx, Qb, fK, fV);

  // 3. tree levels 7..12
  tree_l712<<<32, 64, 0, stream>>>(fK, fV);

  // 4. sparse attention
  attn_kernel<<<dim3(64, 32), 64, 0, stream>>>(Qb, fK, fV, Ob);

  // 5. output projection
  gemm8_out_kernel<<<512, 256, 0, stream>>>(Ob, wox, bo, out);
}

// Round 10
// 155.239 us; speedup vs baseline: 1.2777x; 1.0277x over previous
//
#include <hip/hip_runtime.h>
#include <cstdint>
#include <cstddef>

// ---------------------------------------------------------------------------
// HierarchicalSparseAttention  B=2 L=4096 D=1024 H=16 DH=64
// cvt(weights only) -> QKV GEMM reading f32 activations via async LDS staging
// (f32->bf16 at fragment build; tree levels 1..6 fused) -> tree_l712 ->
// sparse attn -> output GEMM (+bias, f32)
// ---------------------------------------------------------------------------

typedef __bf16 bf16;
typedef __bf16 bf16x8 __attribute__((ext_vector_type(8)));
typedef float  f32x4  __attribute__((ext_vector_type(4)));

#define L_SEQ  4096
#define NFLAT  8192   /* padded 2L-1 = 8191 */

__device__ __forceinline__ int off_l(int l) { return 8192 - (8192 >> l); }

// ---- async global->LDS, 16B per lane; lds base must be wave-uniform --------
__device__ __forceinline__ void glds16(const void* g, void* l) {
  __builtin_amdgcn_global_load_lds(
      (const __attribute__((address_space(1))) unsigned int*)g,
      (__attribute__((address_space(3))) unsigned int*)l, 16, 0, 0);
}

#define MEMFENCE asm volatile("" ::: "memory")
__device__ __forceinline__ void barrier_raw() {
  MEMFENCE; __builtin_amdgcn_s_barrier(); MEMFENCE;
}

// st_16x32 XOR swizzle (involution; permutes 16B chunks, preserves alignment)
__device__ __forceinline__ int swz(int b) { return b ^ (((b >> 9) & 1) << 5); }
// byte addr of (row, col2) in a [R][128B] byte-tile stored as [16][1024B]
// subtiles; col2 in 2-byte units (0..63)
__device__ __forceinline__ int la(int row, int col) {
  return ((((row >> 4) << 1) + (col >> 5)) << 10) + ((row & 15) << 6) + ((col & 31) << 1);
}

// ---------------------------------------------------------------------------
// fp32 -> bf16 for the 4 weight matrices only. grid 256 x 256, grid-stride.
// ---------------------------------------------------------------------------
__global__ __launch_bounds__(256) void cvtw_kernel(
    const float* __restrict__ wq, const float* __restrict__ wk,
    const float* __restrict__ wv, const float* __restrict__ wo,
    bf16* __restrict__ wqx, bf16* __restrict__ wkx, bf16* __restrict__ wvx,
    bf16* __restrict__ wox) {
  for (int i = blockIdx.x * 256 + threadIdx.x; i < 524288; i += 65536) {
    const int t = i >> 17; const int g = i & 131071;
    const float* s = (t == 0) ? wq : (t == 1) ? wk : (t == 2) ? wv : wo;
    bf16*        d = (t == 0) ? wqx : (t == 1) ? wkx : (t == 2) ? wvx : wox;
    const float4 v0 = ((const float4*)s)[(size_t)g * 2];
    const float4 v1 = ((const float4*)s)[(size_t)g * 2 + 1];
    bf16x8 o;
    o[0] = (bf16)v0.x; o[1] = (bf16)v0.y; o[2] = (bf16)v0.z; o[3] = (bf16)v0.w;
    o[4] = (bf16)v1.x; o[5] = (bf16)v1.y; o[6] = (bf16)v1.z; o[7] = (bf16)v1.w;
    *(bf16x8*)(d + (size_t)g * 8) = o;
  }
}

// ---------------------------------------------------------------------------
// QKV GEMM: C(128x128) = A_f32(128xK) * W_bf16(128xK)^T, K=1024.
// A staged as raw f32 bytes (BK=32 tiles, 16KB, byte-shape [128][128B]);
// W staged bf16 (BK=64 tiles, 16KB). Both 2-ring, depth-1 prefetch,
// vmcnt(0)+barrier per step (R7 schedule), swizzled LDS, setprio on MFMA.
// f32->bf16 conversion happens at fragment build (RNE — identical numerics
// to the former standalone cvt kernel).
// 256 thr = 4 waves (2x2); wave 64x64 = 4x4 frags of 16x16x32.
// ---------------------------------------------------------------------------
__device__ __forceinline__ void stage_A32(const float* __restrict__ A,
                                          int tm, int k0, char* buf,
                                          int tid, int wid) {
#pragma unroll
  for (int i = 0; i < 4; i++) {
    const int d  = i * 4096 + tid * 16;
    const int lb = swz(d);
    const int row = ((lb >> 10) >> 1) * 16 + ((lb >> 6) & 15);
    const int col = ((lb >> 10) & 1) * 16 + ((lb & 63) >> 2);   // f32 col
    glds16(A + (size_t)(tm * 128 + row) * 1024 + k0 + col,
           buf + i * 4096 + wid * 1024);
  }
}
__device__ __forceinline__ void stage_B64(const bf16* __restrict__ W,
                                          int tn, int k0, char* buf,
                                          int tid, int wid) {
#pragma unroll
  for (int i = 0; i < 4; i++) {
    const int d  = i * 4096 + tid * 16;
    const int lb = swz(d);
    const int row = ((lb >> 10) >> 1) * 16 + ((lb >> 6) & 15);
    const int col = ((lb >> 10) & 1) * 32 + ((lb & 63) >> 1);   // bf16 col
    glds16(W + (size_t)(tn * 128 + row) * 1024 + k0 + col,
           buf + i * 4096 + wid * 1024);
  }
}

__device__ __forceinline__ void gemmf_core(const float* __restrict__ A,
                                           const bf16* __restrict__ W,
                                           int tm, int tn, char* lds,
                                           f32x4 (&acc)[4][4]) {
  const int tid  = threadIdx.x;
  const int wid  = tid >> 6, lane = tid & 63;
  const int wm   = wid >> 1, wn = wid & 1;
  const int laneR  = lane & 15;
  const int k16    = lane >> 4;          // 0..3
  char* Al = lds;                        // 2 x 16KB
  char* Bl = lds + 32768;                // 2 x 16KB

  stage_A32(A, tm, 0, Al, tid, wid);
  stage_B64(W, tn, 0, Bl, tid, wid);

  for (int s = 0; s < 32; ++s) {
    asm volatile("s_waitcnt vmcnt(0)" ::: "memory");
    barrier_raw();   // stage(s) visible; buffers for s+1 fully consumed
    if (s + 1 < 32) stage_A32(A, tm, (s + 1) << 5, Al + ((s + 1) & 1) * 16384, tid, wid);
    if (!(s & 1) && (s >> 1) + 1 < 16)
      stage_B64(W, tn, ((s >> 1) + 1) << 6, Bl + (((s >> 1) + 1) & 1) * 16384, tid, wid);

    const char* Ab = Al + (s & 1) * 16384;
    const char* Bb = Bl + ((s >> 1) & 1) * 16384;
    const int kc = (s & 1) * 32;         // bf16 col-half within B tile

    bf16x8 af[4], bfr[4];
#pragma unroll
    for (int f = 0; f < 4; f++) {
      const int row = wm * 64 + f * 16 + laneR;
      const f32x4 a0 = *(const f32x4*)(Ab + swz(la(row, k16 * 16)));
      const f32x4 a1 = *(const f32x4*)(Ab + swz(la(row, k16 * 16 + 8)));
      bf16x8 o;
      o[0] = (bf16)a0[0]; o[1] = (bf16)a0[1]; o[2] = (bf16)a0[2]; o[3] = (bf16)a0[3];
      o[4] = (bf16)a1[0]; o[5] = (bf16)a1[1]; o[6] = (bf16)a1[2]; o[7] = (bf16)a1[3];
      af[f] = o;
    }
#pragma unroll
    for (int j = 0; j < 4; j++) {
      const int row = wn * 64 + j * 16 + laneR;
      bfr[j] = *(const bf16x8*)(Bb + swz(la(row, kc + k16 * 8)));
    }

    __builtin_amdgcn_s_setprio(1);
#pragma unroll
    for (int f = 0; f < 4; f++)
#pragma unroll
      for (int j = 0; j < 4; j++)
        acc[f][j] = __builtin_amdgcn_mfma_f32_16x16x32_bf16(af[f], bfr[j], acc[f][j], 0, 0, 0);
    __builtin_amdgcn_s_setprio(0);
  }
}

// XCD-chunked bijective tile map (512 blocks/z, xcd=bid&7): XCD x owns tm in
// [8x,8x+8) for all tn -> per-XCD A working set L2-resident.
__device__ __forceinline__ void tile_map(int bid, int& tm, int& tn) {
  const int xcd = bid & 7, q = bid >> 3;
  tm = xcd * 8 + (q >> 3);
  tn = q & 7;
}

// QKV projections + fused K/V tree levels 1..6. grid = (512, 3).
__global__ __launch_bounds__(256, 2) void gemmf_qkv_kernel(
    const float* __restrict__ qf, const float* __restrict__ kf, const float* __restrict__ vf,
    const bf16* __restrict__ wq, const bf16* __restrict__ wk, const bf16* __restrict__ wv,
    bf16* __restrict__ Qb, bf16* __restrict__ fK, bf16* __restrict__ fV) {
  __shared__ __align__(16) char lds[65536];
  const int z = blockIdx.y;
  const float* A = (z == 0) ? qf : (z == 1) ? kf : vf;
  const bf16*  W = (z == 0) ? wq : (z == 1) ? wk : wv;
  bf16* D        = (z == 0) ? Qb : (z == 1) ? fK : fV;
  const int lstr = (z == 0) ? L_SEQ : NFLAT;
  int tm, tn; tile_map(blockIdx.x, tm, tn);
  f32x4 acc[4][4] = {};
  gemmf_core(A, W, tm, tn, lds, acc);

  const int lane = threadIdx.x & 63, wid = threadIdx.x >> 6;
  const int rl0 = (wid >> 1) * 64 + (lane >> 4) * 4;   // local row
  const int cl0 = (wid & 1) * 64 + (lane & 15);        // local col
#pragma unroll
  for (int i = 0; i < 4; i++)
#pragma unroll
    for (int j = 0; j < 4; j++)
#pragma unroll
      for (int r = 0; r < 4; r++) {
        const int m = tm * 128 + rl0 + i * 16 + r;
        const int n = tn * 128 + cl0 + j * 16;
        const int b = m >> 12, l = m & 4095;
        const int h = n >> 6,  dh = n & 63;
        D[((size_t)(b * 16 + h) * lstr + l) * 64 + dh] = (bf16)acc[i][j][r];
      }

  // ---- fused tree levels 1..6 (K and V blocks only) ----
  if (z != 0) {
    bf16* Ct = (bf16*)lds;                 // [128][132] bf16 = 33792B (<64KB)
    barrier_raw();                         // all waves done reading ring bufs
#pragma unroll
    for (int i = 0; i < 4; i++)
#pragma unroll
      for (int j = 0; j < 4; j++)
#pragma unroll
        for (int r = 0; r < 4; r++)
          Ct[(rl0 + i * 16 + r) * 132 + (cl0 + j * 16)] = (bf16)acc[i][j][r];
    barrier_raw();

    const int g2 = threadIdx.x >> 7;       // 64-leaf group within tile
    const int c  = threadIdx.x & 127;      // local col
    const int h  = tn * 2 + (c >> 6), dh = c & 63;
    const int b  = (tm * 128) >> 12;
    const int lbase = ((tm * 128) & 4095) + g2 * 64;
    const size_t fb = (size_t)(b * 16 + h) * NFLAT * 64 + dh;
    float pk[7];
#pragma unroll
    for (int i = 0; i < 64; i++) {
      float ck = (float)Ct[(g2 * 64 + i) * 132 + c];
#pragma unroll
      for (int l = 1; l <= 6; l++) {
        if (((i + 1) & ((1 << l) - 1)) != 0) { pk[l] = ck; break; }
        ck += pk[l];
        const int j = (lbase + i) >> l;
        D[fb + (size_t)(off_l(l) + j) * 64] =
            (bf16)(z == 1 ? ck * (1.0f / (1 << l)) : ck);
      }
    }
  }
}

// ---------------------------------------------------------------------------
// Output GEMM (bf16 A via global_load_lds, unchanged R7 core) + bias, f32 out.
// ---------------------------------------------------------------------------
#define BUFB 32768   /* 16KB A + 16KB B */

__device__ __forceinline__ void stage_tile(const bf16* __restrict__ A,
                                           const bf16* __restrict__ W,
                                           int tm, int tn, int k0,
                                           char* buf, int tid, int wid) {
  bf16* Ad = (bf16*)buf;
  bf16* Bd = (bf16*)(buf + 16384);
#pragma unroll
  for (int i = 0; i < 4; i++) {
    const int d  = i * 4096 + tid * 16;
    const int lb = swz(d);
    const int row = ((lb >> 10) >> 1) * 16 + ((lb >> 6) & 15);
    const int col = ((lb >> 10) & 1) * 32 + ((lb & 63) >> 1);
    glds16(A + (size_t)(tm * 128 + row) * 1024 + k0 + col, Ad + ((i * 4096 + wid * 1024) >> 1));
    glds16(W + (size_t)(tn * 128 + row) * 1024 + k0 + col, Bd + ((i * 4096 + wid * 1024) >> 1));
  }
}

__device__ __forceinline__ void gemm8_core(const bf16* __restrict__ A,
                                           const bf16* __restrict__ W,
                                           int tm, int tn, char* lds,
                                           f32x4 (&acc)[4][4]) {
  const int tid  = threadIdx.x;
  const int wid  = tid >> 6, lane = tid & 63;
  const int wm   = wid >> 1, wn = wid & 1;
  const int laneR  = lane & 15;
  const int laneC8 = (lane >> 4) * 8;

  stage_tile(A, W, tm, tn, 0, lds, tid, wid);

  for (int u = 0; u < 16; ++u) {
    asm volatile("s_waitcnt vmcnt(0)" ::: "memory");
    barrier_raw();
    if (u + 1 < 16)
      stage_tile(A, W, tm, tn, (u + 1) << 6, lds + ((u + 1) & 1) * BUFB, tid, wid);

    const char* Ab = lds + (u & 1) * BUFB;
    const char* Bb = Ab + 16384;
    bf16x8 af[4][2], bfr[4][2];
#pragma unroll
    for (int f = 0; f < 4; f++)
#pragma unroll
      for (int ks = 0; ks < 2; ks++)
        af[f][ks] = *(const bf16x8*)(Ab + swz(la(wm * 64 + f * 16 + laneR, ks * 32 + laneC8)));
#pragma unroll
    for (int j = 0; j < 4; j++)
#pragma unroll
      for (int ks = 0; ks < 2; ks++)
        bfr[j][ks] = *(const bf16x8*)(Bb + swz(la(wn * 64 + j * 16 + laneR, ks * 32 + laneC8)));

    __builtin_amdgcn_s_setprio(1);
#pragma unroll
    for (int f = 0; f < 4; f++)
#pragma unroll
      for (int j = 0; j < 4; j++)
#pragma unroll
        for (int ks = 0; ks < 2; ks++)
          acc[f][j] = __builtin_amdgcn_mfma_f32_16x16x32_bf16(
              af[f][ks], bfr[j][ks], acc[f][j], 0, 0, 0);
    __builtin_amdgcn_s_setprio(0);
  }
}

__global__ __launch_bounds__(256, 2) void gemm8_out_kernel(
    const bf16* __restrict__ Ob, const bf16* __restrict__ wo,
    const float* __restrict__ bo, float* __restrict__ out) {
  __shared__ __align__(16) char lds[2 * BUFB];
  int tm, tn; tile_map(blockIdx.x, tm, tn);
  f32x4 acc[4][4] = {};
  gemm8_core(Ob, wo, tm, tn, lds, acc);
  const int lane = threadIdx.x & 63, wid = threadIdx.x >> 6;
  const int m0 = tm * 128 + (wid >> 1) * 64 + (lane >> 4) * 4;
  const int n0 = tn * 128 + (wid & 1) * 64 + (lane & 15);
#pragma unroll
  for (int i = 0; i < 4; i++)
#pragma unroll
    for (int j = 0; j < 4; j++)
#pragma unroll
      for (int r = 0; r < 4; r++) {
        const int m = m0 + i * 16 + r;
        const int n = n0 + j * 16;
        out[(size_t)m * 1024 + n] = acc[i][j][r] + bo[n];
      }
}

// ---------------------------------------------------------------------------
// Tree levels 7..12 from level 6. Block = 1 wave per bh, lane = column d.
// grid = 32
// ---------------------------------------------------------------------------
__global__ __launch_bounds__(64) void tree_l712(bf16* __restrict__ fK, bf16* __restrict__ fV) {
  __shared__ float Ks[64 * 64];
  __shared__ float Vs[64 * 64];
  const int bh = blockIdx.x, d = threadIdx.x;
  const size_t fb = (size_t)bh * NFLAT * 64;
#pragma unroll 8
  for (int i = 0; i < 64; i++) {
    Ks[i * 64 + d] = (float)fK[fb + (size_t)(8064 + i) * 64 + d];  // off_l(6)=8064
    Vs[i * 64 + d] = (float)fV[fb + (size_t)(8064 + i) * 64 + d];
  }
#pragma unroll
  for (int l = 7; l <= 12; l++) {
    const int cnt = 4096 >> l;
    for (int j = 0; j < cnt; j++) {
      const float k = (Ks[(2 * j) * 64 + d] + Ks[(2 * j + 1) * 64 + d]) * 0.5f;
      const float v =  Vs[(2 * j) * 64 + d] + Vs[(2 * j + 1) * 64 + d];
      Ks[j * 64 + d] = k;
      Vs[j * 64 + d] = v;
      fK[fb + (size_t)(off_l(l) + j) * 64 + d] = (bf16)k;
      fV[fb + (size_t)(off_l(l) + j) * 64 + d] = (bf16)v;
    }
  }
}

// ---------------------------------------------------------------------------
// Sparse attention (unchanged from round 9): 68 shared tree rows in LDS,
// level-0 rows direct from global. grid = (64, 32)
// ---------------------------------------------------------------------------
__global__ __launch_bounds__(64) void attn_kernel(
    const bf16* __restrict__ Qb, const bf16* __restrict__ fK,
    const bf16* __restrict__ fV, bf16* __restrict__ Ob) {
  __shared__ __align__(16) unsigned short Kl[68 * 64];
  __shared__ __align__(16) unsigned short Vl[68 * 64];
  const int t0  = blockIdx.x * 64;
  const int bh  = blockIdx.y;
  const int tid = threadIdx.x;
  const size_t fb = (size_t)bh * NFLAT * 64;

  for (int u = tid; u < 68 * 8; u += 64) {
    const int r = u >> 3, c = u & 7;
    int flat;
    if      (r < 32) flat = 4096 + (t0 >> 1) + r;
    else if (r < 48) flat = 6144 + (t0 >> 2) + (r - 32);
    else if (r < 56) flat = 7168 + (t0 >> 3) + (r - 48);
    else if (r < 60) flat = 7680 + (t0 >> 4) + (r - 56);
    else if (r < 62) flat = 7936 + (t0 >> 5) + (r - 60);
    else { const int l = r - 56; flat = (8192 - (8192 >> l) + (t0 >> l)) ^ 1; }
    const int cc = c ^ (r & 7);
    const uint4 kk = *(const uint4*)((const char*)(fK + fb + (size_t)flat * 64) + c * 16);
    const uint4 vv = *(const uint4*)((const char*)(fV + fb + (size_t)flat * 64) + c * 16);
    *(uint4*)((char*)Kl + r * 128 + cc * 16) = kk;
    *(uint4*)((char*)Vl + r * 128 + cc * 16) = vv;
  }
  __syncthreads();

  const int n = t0 + tid;
  int rows[13];
#pragma unroll
  for (int l = 1; l < 12; l++) {
    int r;
    if (l <= 5) r = (64 - (128 >> l)) + (((n >> l) ^ 1) - (t0 >> l));
    else        r = 62 + (l - 6);
    rows[l + 1] = r;
  }

  float q[64];
  const bf16* Qr = Qb + ((size_t)bh * L_SEQ + n) * 64;
#pragma unroll
  for (int c = 0; c < 8; c++) {
    bf16x8 v = *(const bf16x8*)(Qr + c * 8);
#pragma unroll
    for (int j = 0; j < 8; j++) q[c * 8 + j] = (float)v[j];
  }

  float lg[13];
  {
    const bf16* Ks0 = fK + fb + (size_t)(t0 + tid) * 64;
    const bf16* Kn0 = fK + fb + (size_t)(t0 + (tid ^ 1)) * 64;
    float a0 = 0.f, a1 = 0.f;
#pragma unroll
    for (int c = 0; c < 8; c++) {
      const bf16x8 s = *(const bf16x8*)(Ks0 + c * 8);
      const bf16x8 t = *(const bf16x8*)(Kn0 + c * 8);
#pragma unroll
      for (int j = 0; j < 8; j++) { a0 += q[c * 8 + j] * (float)s[j]; a1 += q[c * 8 + j] * (float)t[j]; }
    }
    lg[0] = a0 * 0.125f; lg[1] = a1 * 0.125f;
  }
#pragma unroll
  for (int v = 2; v < 13; v++) {
    const int r = rows[v];
    float a = 0.f;
#pragma unroll
    for (int c = 0; c < 8; c++) {
      const int cc = c ^ (r & 7);
      const bf16x8 kv = *(const bf16x8*)((const char*)Kl + r * 128 + cc * 16);
#pragma unroll
      for (int j = 0; j < 8; j++) a += q[c * 8 + j] * (float)kv[j];
    }
    lg[v] = a * 0.125f;
  }
#pragma unroll
  for (int v = 1; v < 13; v++)
    if (!((n >> (v - 1)) & 1)) lg[v] = -1e30f;

  float mx = lg[0];
#pragma unroll
  for (int v = 1; v < 13; v++) mx = fmaxf(mx, lg[v]);
  float w[13], s = 0.f;
#pragma unroll
  for (int v = 0; v < 13; v++) { w[v] = __expf(lg[v] - mx); s += w[v]; }
  const float inv = 1.0f / s;

  float o[64];
#pragma unroll
  for (int d = 0; d < 64; d++) o[d] = 0.f;
  {
    const bf16* Vs0 = fV + fb + (size_t)(t0 + tid) * 64;
    const bf16* Vn0 = fV + fb + (size_t)(t0 + (tid ^ 1)) * 64;
    const float w0 = w[0], w1 = w[1];
#pragma unroll
    for (int c = 0; c < 8; c++) {
      const bf16x8 s0 = *(const bf16x8*)(Vs0 + c * 8);
      const bf16x8 t1 = *(const bf16x8*)(Vn0 + c * 8);
#pragma unroll
      for (int j = 0; j < 8; j++) o[c * 8 + j] += w0 * (float)s0[j] + w1 * (float)t1[j];
    }
  }
#pragma unroll
  for (int v = 2; v < 13; v++) {
    const int r = rows[v];
    const float wv = w[v];
#pragma unroll
    for (int c = 0; c < 8; c++) {
      const int cc = c ^ (r & 7);
      const bf16x8 vv = *(const bf16x8*)((const char*)Vl + r * 128 + cc * 16);
#pragma unroll
      for (int j = 0; j < 8; j++) o[c * 8 + j] += wv * (float)vv[j];
    }
  }

  bf16* Or = Ob + ((size_t)(bh >> 4) * L_SEQ + n) * 1024 + (size_t)(bh & 15) * 64;
#pragma unroll
  for (int c = 0; c < 8; c++) {
    bf16x8 ov;
#pragma unroll
    for (int j = 0; j < 8; j++) ov[j] = (bf16)(o[c * 8 + j] * inv);
    *(bf16x8*)(Or + c * 8) = ov;
  }
}

// ---------------------------------------------------------------------------
extern "C" void kernel_launch(void* const* d_in, const int* in_sizes, int n_in,
                              void* d_out, int out_size, void* d_ws, size_t ws_size,
                              hipStream_t stream) {
  const float* query = (const float*)d_in[0];
  const float* key   = (const float*)d_in[1];
  const float* value = (const float*)d_in[2];
  const float* Wq    = (const float*)d_in[3];
  const float* Wk    = (const float*)d_in[4];
  const float* Wv    = (const float*)d_in[5];
  const float* Wo    = (const float*)d_in[6];
  const float* bo    = (const float*)d_in[7];
  float* out = (float*)d_out;

  char* ws = (char*)d_ws;
  size_t off = 0;
  auto take = [&](size_t bytes) -> void* {
    void* p = ws + off;
    off += (bytes + 255) & ~(size_t)255;
    return p;
  };
  const size_t WB = (size_t)1024 * 1024 * 2;   // 2.10 MB
  bf16* wqx = (bf16*)take(WB);
  bf16* wkx = (bf16*)take(WB);
  bf16* wvx = (bf16*)take(WB);
  bf16* wox = (bf16*)take(WB);
  bf16* Qb  = (bf16*)take((size_t)32 * L_SEQ * 64 * 2);   // 16.78 MB
  bf16* fK  = (bf16*)take((size_t)32 * NFLAT * 64 * 2);   // 33.55 MB
  bf16* fV  = (bf16*)take((size_t)32 * NFLAT * 64 * 2);   // 33.55 MB
  bf16* Ob  = (bf16*)take((size_t)8192 * 1024 * 2);       // 16.78 MB
  (void)in_sizes; (void)n_in; (void)out_size; (void)ws_size;

  // 1. weights fp32 -> bf16
  cvtw_kernel<<<256, 256, 0, stream>>>(Wq, Wk, Wv, Wo, wqx, wkx, wvx, wox);

  // 2. Q/K/V projections reading f32 activations directly + tree levels 1..6
  gemmf_qkv_kernel<<<dim3(512, 3), 256, 0, stream>>>(
      query, key, value, wqx, wkx, wvx, Qb, fK, fV);

  // 3. tree levels 7..12
  tree_l712<<<32, 64, 0, stream>>>(fK, fV);

  // 4. sparse attention
  attn_kernel<<<dim3(64, 32), 64, 0, stream>>>(Qb, fK, fV, Ob);

  // 5. output projection
  gemm8_out_kernel<<<512, 256, 0, stream>>>(Ob, wox, bo, out);
}